// Round 5
// baseline (873.727 us; speedup 1.0000x reference)
//
#include <hip/hip_runtime.h>
#include <cstdint>
#include <cstddef>

#define NN 50000
#define EE 1000000
#define NBK 196          // dst buckets (dst>>8), 196*256 = 50176 >= NN
#define PWAVES 5120      // persistent waves for gather kernels (1280 blocks * 4)

typedef __attribute__((ext_vector_type(8))) short bf16x8;
typedef __attribute__((ext_vector_type(4))) short s16x4;
typedef __attribute__((ext_vector_type(4))) float f32x4;
typedef _Float16 f16;
typedef __attribute__((ext_vector_type(2))) _Float16 f16x2;
typedef __attribute__((ext_vector_type(4))) _Float16 f16x4;
typedef __attribute__((ext_vector_type(8))) _Float16 f16x8;

// truncation split: v == bf16(hi) + ~bf16(lo), residual ~2^-16 rel
__device__ __forceinline__ void split2(float v, short& hi, short& lo) {
    union { float f; unsigned int u; } a; a.f = v;
    unsigned short h16 = (unsigned short)(a.u >> 16);
    union { unsigned int u; float f; } hf; hf.u = ((unsigned int)h16) << 16;
    union { float f; unsigned int u; } b; b.f = v - hf.f;
    hi = (short)h16;
    lo = (short)(b.u >> 16);
}

// relu(p+q) in packed f16 (v_pk_add_f16 + v_pk_max_f16)
__device__ __forceinline__ f16x8 relupq(f16x8 p, f16x8 q) {
    f16x8 s = p + q;
    f16x8 z = {};
#if __has_builtin(__builtin_elementwise_max)
    return __builtin_elementwise_max(s, z);
#else
    f16x8 r;
#pragma unroll
    for (int j = 0; j < 8; j++) r[j] = (s[j] > (f16)0.f) ? s[j] : (f16)0.f;
    return r;
#endif
}

// ---------- workspace layout (byte offsets) ----------
#define OFF_WHL    ((size_t)0)          // 2*1024*64 bf16 = 262144
#define OFF_WSPP   ((size_t)262144)     // 64*4 f32
#define OFF_BIAS01 ((size_t)263168)     // 64 f32
#define OFF_W1PQT  ((size_t)263424)     // 3*64*128 f32
#define OFF_BIASPQ ((size_t)361728)     // 3*128 f32
#define OFF_WSAGET ((size_t)363264)     // 128*64 f32
#define OFF_BIAS21 ((size_t)396032)     // 64 f32
#define OFF_BNF    ((size_t)396288)     // 3*192 f32 (+pad to 2560)
#define OFF_W2BF   ((size_t)398848)     // 3*64*64 f16 = 24576
#define OFF_INVC4  ((size_t)423424)     // N*4 f32 = 800000 {ic1,ic2,ic3,0}
#define OFF_PZ4    ((size_t)1223424)    // N*4 f32 = 800000 {p1,p2,p3,zsum}
#define OFF_RP     ((size_t)2023424)    // (NN+1) i32 (+pad 200064)
#define OFF_PARTS  ((size_t)2223488)    // 256 i32 (+pad 4096)
#define OFF_DEG    ((size_t)2227584)    // N i32 (+pad 200064)
#define OFF_GHEAD  ((size_t)2427648)    // NBK i32 (+pad 4096)
#define OFF_SORT   ((size_t)2431744)    // E i32 = 4000000 (src | attr<<16)
#define OFF_H      ((size_t)6431744)    // N*64 f32 = 12800000
#define OFF_PI     ((size_t)19231744)   // N*192 f16 = 19200000 (P, interleaved 3 branches)
#define OFF_QI     ((size_t)38431744)   // N*192 f16 = 19200000 (Q, interleaved)
#define OFF_Y1I    ((size_t)57631744)   // N*192 f16 = 19200000 (end 76831744)
#define OFF_EBUCK  OFF_H                // overlay: E u32, dead before k_h
#define OFF_AGGI   OFF_PI               // overlay: N*192 f16, Pi dead after edgeconv

// ---------- K1: weight prep / folding ----------
__global__ __launch_bounds__(256) void k_prep(
    const float* __restrict__ Wspf, const float* __restrict__ bspf,
    const float* __restrict__ W011, const float* __restrict__ b011,
    const float* __restrict__ W012, const float* __restrict__ b012,
    const float* __restrict__ bn01,
    const float* __restrict__ e1W1, const float* __restrict__ e1b1,
    const float* __restrict__ e1b2, const float* __restrict__ bn11,
    const float* __restrict__ e2W1, const float* __restrict__ e2b1,
    const float* __restrict__ e2b2, const float* __restrict__ bn12,
    const float* __restrict__ e3W1, const float* __restrict__ e3b1,
    const float* __restrict__ e3b2, const float* __restrict__ bn13,
    const float* __restrict__ e1W2, const float* __restrict__ e2W2,
    const float* __restrict__ e3W2,
    const float* __restrict__ s21Wl, const float* __restrict__ s21bl,
    const float* __restrict__ s21Wr, const float* __restrict__ bn21,
    unsigned short* __restrict__ Whl, float* __restrict__ WspP, float* __restrict__ bias01,
    float* __restrict__ W1pqT, float* __restrict__ biasPQ,
    float* __restrict__ WsageT, float* __restrict__ bias21, float* __restrict__ bnf,
    f16* __restrict__ W2h)
{
    int idx = blockIdx.x * 256 + threadIdx.x;
    if (idx < 131072) {
        int hl = idx >> 16;
        int r = idx & 65535;
        int kchunk = r >> 11;
        int r2 = r & 2047;
        int blk = r2 >> 9;
        int r3 = r2 & 511;
        int lane = r3 >> 3;
        int j = r3 & 7;
        int n = lane & 15, quad = lane >> 4;
        int k = kchunk * 32 + quad * 8 + j;
        int c = blk * 16 + n;
        float s = bn01[c] * rsqrtf(bn01[192 + c] + 1e-5f);
        float w = ((k < 512) ? W012[c * 512 + k] : W011[c * 576 + (k - 512)]) * s;
        short hi, lo;
        split2(w, hi, lo);
        Whl[idx] = (unsigned short)(hl ? lo : hi);
    } else if (idx < 131072 + 24576) {
        int r = idx - 131072;
        int b = r >> 13; r &= 8191;
        int k = r >> 7, cp = r & 127;
        const float* W1 = (b == 0) ? e1W1 : (b == 1) ? e2W1 : e3W1;
        float val;
        if (cp < 64) val = W1[cp * 128 + k] - W1[cp * 128 + 64 + k];
        else         val = W1[(cp - 64) * 128 + 64 + k];
        W1pqT[b * 8192 + k * 128 + cp] = val;
    } else if (idx < 131072 + 24576 + 8192) {
        int r = idx - (131072 + 24576);
        int k = r >> 6, c = r & 63;
        float s = bn21[c] * rsqrtf(bn21[192 + c] + 1e-5f);
        float w = (k < 64) ? s21Wl[c * 64 + k] : s21Wr[c * 64 + (k - 64)];
        WsageT[k * 64 + c] = w * s;
    } else if (idx < 131072 + 24576 + 8192 + 64) {
        int c = idx - (131072 + 24576 + 8192);
        float s01 = bn01[c] * rsqrtf(bn01[192 + c] + 1e-5f);
        float wsp0 = 0.f, wsp1 = 0.f, wsp2 = 0.f, wsp3 = 0.f, bacc = 0.f;
        for (int j = 0; j < 64; j++) {
            float w = W011[c * 576 + 512 + j];
            wsp0 += w * Wspf[j * 4 + 0];
            wsp1 += w * Wspf[j * 4 + 1];
            wsp2 += w * Wspf[j * 4 + 2];
            wsp3 += w * Wspf[j * 4 + 3];
            bacc += w * bspf[j];
        }
        WspP[c * 4 + 0] = wsp0 * s01; WspP[c * 4 + 1] = wsp1 * s01;
        WspP[c * 4 + 2] = wsp2 * s01; WspP[c * 4 + 3] = wsp3 * s01;
        bias01[c] = (b011[c] + b012[c] + bacc) * s01 + (bn01[64 + c] - bn01[128 + c] * s01);
        float s21 = bn21[c] * rsqrtf(bn21[192 + c] + 1e-5f);
        bias21[c] = s21bl[c] * s21 + (bn21[64 + c] - bn21[128 + c] * s21);
        const float* b1a[3] = { e1b1, e2b1, e3b1 };
        const float* b2a[3] = { e1b2, e2b2, e3b2 };
        const float* bna[3] = { bn11, bn12, bn13 };
#pragma unroll
        for (int b = 0; b < 3; b++) {
            float s = bna[b][c] * rsqrtf(bna[b][192 + c] + 1e-5f);
            float tr = bna[b][64 + c] - bna[b][128 + c] * s;
            bnf[b * 192 + c] = s;
            bnf[b * 192 + 64 + c] = b2a[b][c] * s + tr;
            bnf[b * 192 + 128 + c] = tr;
            biasPQ[b * 128 + c] = b1a[b][c];
            biasPQ[b * 128 + 64 + c] = 0.f;
        }
    } else if (idx < 131072 + 24576 + 8192 + 64 + 12288) {
        int r = idx - (131072 + 24576 + 8192 + 64);
        int b = r >> 12, i = r & 4095;
        const float* W2 = (b == 0) ? e1W2 : (b == 1) ? e2W2 : e3W2;
        W2h[b * 4096 + i] = (f16)W2[i];
    }
}

// ---------- degree histogram (single, all edges) ----------
__global__ __launch_bounds__(256) void k_hist(
    const int* __restrict__ dst, int* __restrict__ deg)
{
    int e = blockIdx.x * 256 + threadIdx.x;
    if (e < EE) atomicAdd(&deg[dst[e]], 1);
}

__global__ __launch_bounds__(256) void k_psum(const int* __restrict__ deg, int* __restrict__ parts)
{
    int i = blockIdx.x * 256 + threadIdx.x;
    int v = (i < NN) ? deg[i] : 0;
#pragma unroll
    for (int off = 32; off > 0; off >>= 1) v += __shfl_xor(v, off);
    __shared__ int ws4[4];
    int wid = threadIdx.x >> 6;
    if ((threadIdx.x & 63) == 0) ws4[wid] = v;
    __syncthreads();
    if (threadIdx.x == 0)
        parts[blockIdx.x] = ws4[0] + ws4[1] + ws4[2] + ws4[3];
}

__global__ __launch_bounds__(256) void k_pscan(int* __restrict__ parts)
{
    __shared__ int sbuf[256];
    int tid = threadIdx.x;
    int v = (tid < NBK) ? parts[tid] : 0;
    sbuf[tid] = v;
    __syncthreads();
    for (int off = 1; off < 256; off <<= 1) {
        int t = (tid >= off) ? sbuf[tid - off] : 0;
        __syncthreads();
        sbuf[tid] += t;
        __syncthreads();
    }
    if (tid < NBK) parts[tid] = sbuf[tid] - v;  // exclusive
}

__global__ __launch_bounds__(256) void k_scanfix(
    const int* __restrict__ deg, const int* __restrict__ parts, int* __restrict__ rowptr)
{
    __shared__ int sbuf[256];
    int tid = threadIdx.x;
    int i = blockIdx.x * 256 + tid;
    int v = (i < NN) ? deg[i] : 0;
    sbuf[tid] = v;
    __syncthreads();
    for (int off = 1; off < 256; off <<= 1) {
        int t = (tid >= off) ? sbuf[tid - off] : 0;
        __syncthreads();
        sbuf[tid] += t;
        __syncthreads();
    }
    int base = parts[blockIdx.x];
    if (i < NN)      rowptr[i] = base + sbuf[tid] - v;
    if (i == NN - 1) rowptr[NN] = base + sbuf[tid];
}

__global__ __launch_bounds__(256) void k_gheadinit(
    const int* __restrict__ rp, int* __restrict__ ghead)
{
    int t = threadIdx.x;
    if (t < NBK) ghead[t] = rp[t * 256];
}

// ---------- bucketed sort pass A: partition edges into dst-buckets ----------
__global__ __launch_bounds__(256) void k_bucketA(
    const int* __restrict__ src, const int* __restrict__ dst, const int* __restrict__ attr,
    int* __restrict__ ghead, unsigned int* __restrict__ ebuck)
{
    __shared__ int hist[NBK];
    __shared__ int head[NBK];
    int tid = threadIdx.x;
    if (tid < NBK) hist[tid] = 0;
    __syncthreads();
    int base_e = blockIdx.x * 4096;
    unsigned int word[16]; int bkt[16];
#pragma unroll
    for (int k = 0; k < 16; k++) {
        int e = base_e + k * 256 + tid;
        if (e < EE) {
            int d = dst[e], s = src[e], a = attr[e] + 1;
            int b = d >> 8;
            word[k] = (unsigned)s | ((unsigned)a << 16) | ((unsigned)(d & 255) << 18);
            bkt[k] = b;
            atomicAdd(&hist[b], 1);
        } else { bkt[k] = -1; word[k] = 0; }
    }
    __syncthreads();
    if (tid < NBK) {
        int c = hist[tid];
        head[tid] = c ? atomicAdd(&ghead[tid], c) : 0;
    }
    __syncthreads();
#pragma unroll
    for (int k = 0; k < 16; k++) {
        if (bkt[k] >= 0) {
            int pos = atomicAdd(&head[bkt[k]], 1);
            ebuck[pos] = word[k];
        }
    }
}

// ---------- bucketed sort pass B: exact dst sort within bucket ----------
__global__ __launch_bounds__(256) void k_bucketB(
    const int* __restrict__ rp, const unsigned int* __restrict__ ebuck,
    int* __restrict__ sorted)
{
    __shared__ int sbuf[256];
    __shared__ int head[256];
    int b = blockIdx.x, tid = threadIdx.x;
    int n0 = b * 256;
    int n1 = n0 + 256; if (n1 > NN) n1 = NN;
    int r0 = rp[n0];
    int r1 = rp[n1];
    sbuf[tid] = 0;
    __syncthreads();
    for (int e = r0 + tid; e < r1; e += 256)
        atomicAdd(&sbuf[(ebuck[e] >> 18) & 255], 1);
    __syncthreads();
    int v = sbuf[tid];
    for (int off = 1; off < 256; off <<= 1) {
        int t = (tid >= off) ? sbuf[tid - off] : 0;
        __syncthreads();
        sbuf[tid] += t;
        __syncthreads();
    }
    head[tid] = r0 + sbuf[tid] - v;
    __syncthreads();
    for (int e = r0 + tid; e < r1; e += 256) {
        unsigned int w = ebuck[e];
        int pos = atomicAdd(&head[(w >> 18) & 255], 1);
        sorted[pos] = (int)(w & 0x3FFFFu);   // src | attr<<16
    }
}

// ---------- K2: h = relu(fold_bn01(x @ Wc')) ----------
__global__ __launch_bounds__(256) void k_h(
    const float* __restrict__ x, const unsigned short* __restrict__ Whl,
    const float* __restrict__ WspP, const float* __restrict__ bias01,
    float* __restrict__ h)
{
    __shared__ unsigned short hib[2][4096];
    __shared__ unsigned short lob[2][4096];
    int tid = threadIdx.x;
    int w = tid >> 6, l = tid & 63;
    int tile = blockIdx.x;
    int m = l & 15, quad = l >> 4;
    int blk = w;
    const unsigned short* Wh = Whl;
    const unsigned short* Wl = Whl + 65536;
    const size_t xbase = (size_t)tile * 16 * 1028;

    int oct_w = l >> 1, off_w = (l & 1) * 4;

    f32x4 g[4];
#pragma unroll
    for (int p = 0; p < 4; p++)
        g[p] = *(const f32x4*)(x + xbase + (size_t)(p * 4 + w) * 1028 + l * 4);
#pragma unroll
    for (int p = 0; p < 4; p++) {
        int r = p * 4 + w;
        int op = r * 256 + (oct_w ^ (r & 7)) * 8 + off_w;
        s16x4 h4, l4;
#pragma unroll
        for (int i = 0; i < 4; i++) { short hi, lo; split2(g[p][i], hi, lo); h4[i] = hi; l4[i] = lo; }
        *(s16x4*)(&hib[0][op]) = h4;
        *(s16x4*)(&lob[0][op]) = l4;
    }
    __syncthreads();

    f32x4 acc = { 0.f, 0.f, 0.f, 0.f };
    for (int c = 0; c < 4; c++) {
        if (c < 3) {
#pragma unroll
            for (int p = 0; p < 4; p++)
                g[p] = *(const f32x4*)(x + xbase + (size_t)(p * 4 + w) * 1028 + (c + 1) * 256 + l * 4);
        }
        int buf = c & 1;
        const unsigned short* hp = &hib[buf][m * 256];
        const unsigned short* lp = &lob[buf][m * 256];
        int msw = m & 7;
#pragma unroll
        for (int ks = 0; ks < 8; ks++) {
            int oct = ks * 4 + quad;
            int ao = (oct ^ msw) * 8;
            bf16x8 xh = *(const bf16x8*)(hp + ao);
            bf16x8 xl = *(const bf16x8*)(lp + ao);
            int fb = (c * 8 + ks) * 2048 + blk * 512 + l * 8;
            bf16x8 bh = *(const bf16x8*)(Wh + fb);
            bf16x8 bl = *(const bf16x8*)(Wl + fb);
            acc = __builtin_amdgcn_mfma_f32_16x16x32_bf16(xh, bh, acc, 0, 0, 0);
            acc = __builtin_amdgcn_mfma_f32_16x16x32_bf16(xl, bh, acc, 0, 0, 0);
            acc = __builtin_amdgcn_mfma_f32_16x16x32_bf16(xh, bl, acc, 0, 0, 0);
        }
        if (c < 3) {
            int nbuf = (c + 1) & 1;
#pragma unroll
            for (int p = 0; p < 4; p++) {
                int r = p * 4 + w;
                int op = r * 256 + (oct_w ^ (r & 7)) * 8 + off_w;
                s16x4 h4, l4;
#pragma unroll
                for (int i = 0; i < 4; i++) { short hi, lo; split2(g[p][i], hi, lo); h4[i] = hi; l4[i] = lo; }
                *(s16x4*)(&hib[nbuf][op]) = h4;
                *(s16x4*)(&lob[nbuf][op]) = l4;
            }
            __syncthreads();
        }
    }

    int ch = blk * 16 + m;
    f32x4 wsp = *(const f32x4*)(WspP + ch * 4);
    float bia = bias01[ch];
#pragma unroll
    for (int r = 0; r < 4; r++) {
        int row = tile * 16 + quad * 4 + r;
        f32x4 sp = *(const f32x4*)(x + (size_t)row * 1028 + 1024);
        float a = acc[r] + sp[0] * wsp[0] + sp[1] * wsp[1]
                + sp[2] * wsp[2] + sp[3] * wsp[3] + bia;
        h[(size_t)row * 64 + ch] = fmaxf(a, 0.f);
    }
}

// ---------- K4: all 3 branches fused: P = h @ W1p' + b1 (f16), Q = h @ W1q' (f16) ----------
__global__ __launch_bounds__(256) void k_pq(
    const float* __restrict__ h, const float* __restrict__ WT3,
    const float* __restrict__ biasPQ, f16* __restrict__ Pi, f16* __restrict__ Qi)
{
    __shared__ float wt[64 * 128];
    __shared__ float xt[64 * 68];
    int tid = threadIdx.x;
    int m0 = blockIdx.x * 64;
    int cg = tid & 31, rg = tid >> 5;
#pragma unroll
    for (int i = 0; i < 4; i++) {
        int li = i * 256 + tid;
        int rr = li >> 4, q = li & 15;
        int row = m0 + rr;
        float4 u = make_float4(0.f, 0.f, 0.f, 0.f);
        if (row < NN) u = *(const float4*)(h + (size_t)row * 64 + q * 4);
        *(float4*)(xt + rr * 68 + q * 4) = u;
    }
    for (int b = 0; b < 3; b++) {
        __syncthreads();
#pragma unroll
        for (int i = 0; i < 8; i++)
            ((float4*)wt)[i * 256 + tid] = ((const float4*)(WT3 + b * 8192))[i * 256 + tid];
        __syncthreads();
        float acc[8][4];
#pragma unroll
        for (int r = 0; r < 8; r++)
#pragma unroll
            for (int j = 0; j < 4; j++) acc[r][j] = 0.f;
#pragma unroll 8
        for (int k = 0; k < 64; k++) {
            float4 wv = *(const float4*)(wt + k * 128 + cg * 4);
#pragma unroll
            for (int r = 0; r < 8; r++) {
                float xv = xt[(rg * 8 + r) * 68 + k];
                acc[r][0] += xv * wv.x; acc[r][1] += xv * wv.y;
                acc[r][2] += xv * wv.z; acc[r][3] += xv * wv.w;
            }
        }
        const float* biasP = biasPQ + b * 128;
#pragma unroll
        for (int r = 0; r < 8; r++) {
            int row = m0 + rg * 8 + r;
            if (row < NN) {
                if (cg < 16) {               // P half (+bias), fp16
                    f16x4 res;
#pragma unroll
                    for (int j = 0; j < 4; j++)
                        res[j] = (f16)(acc[r][j] + biasP[cg * 4 + j]);
                    *(f16x4*)(Pi + (size_t)row * 192 + b * 64 + cg * 4) = res;
                } else {                     // Q half, fp16
                    f16x4 res;
#pragma unroll
                    for (int j = 0; j < 4; j++)
                        res[j] = (f16)acc[r][j];
                    *(f16x4*)(Qi + (size_t)row * 192 + b * 64 + (cg - 16) * 4) = res;
                }
            }
        }
    }
}

// MFMA + masked-max accumulate via addend (AM[r] in {0, -3e38}); W2 frags from LDS
#define ECV_BR_LDS(B, AF0, AF1, AM, ACC)                                           \
    {                                                                              \
        _Pragma("unroll") for (int blk = 0; blk < 4; blk++) {                      \
            f32x4 c = { 0.f, 0.f, 0.f, 0.f };                                      \
            f16x8 w0 = *(const f16x8*)(w2s + ((B) * 8 + blk * 2 + 0) * 512 + quad * 128 + m * 8); \
            f16x8 w1 = *(const f16x8*)(w2s + ((B) * 8 + blk * 2 + 1) * 512 + quad * 128 + m * 8); \
            c = __builtin_amdgcn_mfma_f32_16x16x32_f16(AF0, w0, c, 0, 0, 0);       \
            c = __builtin_amdgcn_mfma_f32_16x16x32_f16(AF1, w1, c, 0, 0, 0);       \
            _Pragma("unroll") for (int r = 0; r < 4; r++)                          \
                ACC[blk][r] = fmaxf(ACC[blk][r], c[r] + AM[r]);                    \
        }                                                                          \
    }

#define ECV_EPI(B, ACC, CNT)                                                       \
    {                                                                              \
        float red[4];                                                              \
        _Pragma("unroll") for (int blk = 0; blk < 4; blk++) {                      \
            float rv = fmaxf(fmaxf(ACC[blk][0], ACC[blk][1]),                      \
                             fmaxf(ACC[blk][2], ACC[blk][3]));                     \
            rv = fmaxf(rv, __shfl_xor(rv, 16));                                    \
            rv = fmaxf(rv, __shfl_xor(rv, 32));                                    \
            red[blk] = rv;                                                         \
        }                                                                          \
        float mx = red[quad];                                                      \
        const float* scb = bnf + (B) * 192;                                        \
        float outv = ((CNT) > 0) ? fmaxf(fmaf(mx, scb[lane], scb[64 + lane]), 0.f) \
                                 : fmaxf(scb[128 + lane], 0.f);                    \
        y1i[(size_t)v * 192 + (B) * 64 + lane] = (f16)outv;                        \
    }

// ---------- K5: fused 3-branch EdgeConv; persistent waves ----------
__global__ __launch_bounds__(256) void k_edgeconv_f(
    const int* __restrict__ rowptr, const int* __restrict__ sorted,
    const f16* __restrict__ Pi, const f16* __restrict__ Qi,
    const f16* __restrict__ W2h,               // 3*64*64 f16
    const float* __restrict__ bnf,             // 3*192
    f16* __restrict__ y1i, float* __restrict__ invc4)
{
    __shared__ f16 w2s[8192];                  // branches 0,1 : 16 frags * 512 halves, bank-permuted
    int tid = threadIdx.x;
#pragma unroll
    for (int u0 = 0; u0 < 4; u0++) {
        int u = u0 * 256 + tid;                // 0..1023
        int frag = u >> 6;                     // b*8 + blk*2 + kc   (b in {0,1})
        int rem = u & 63;
        int m2 = rem >> 2, qd = rem & 3;
        int bb = frag >> 3, blk = (frag >> 1) & 3, kc = frag & 1;
        *(int4*)(w2s + frag * 512 + qd * 128 + m2 * 8) =
            *(const int4*)(W2h + (bb * 64 + blk * 16 + m2) * 64 + kc * 32 + qd * 8);
    }
    __syncthreads();

    int wid = tid >> 6, lane = tid & 63;
    int m = lane & 15, quad = lane >> 4;
    int gw = blockIdx.x * 4 + wid;             // persistent wave id, PWAVES total

    // branch-2 (seg3, all edges) W2 fragments in registers
    f16x8 wf3[4][2];
#pragma unroll
    for (int blk = 0; blk < 4; blk++)
#pragma unroll
        for (int kc = 0; kc < 2; kc++)
            wf3[blk][kc] = *(const f16x8*)(W2h + 2 * 4096 + (blk * 16 + m) * 64 + kc * 32 + quad * 8);

    for (int v = gw; v < NN; v += PWAVES) {
        const f16* pr = Pi + (size_t)v * 192;
        f16x8 pl0 = *(const f16x8*)(pr + 0   + quad * 8);
        f16x8 ph0 = *(const f16x8*)(pr + 32  + quad * 8);
        f16x8 pl1 = *(const f16x8*)(pr + 64  + quad * 8);
        f16x8 ph1 = *(const f16x8*)(pr + 96  + quad * 8);
        f16x8 pl2 = *(const f16x8*)(pr + 128 + quad * 8);
        f16x8 ph2 = *(const f16x8*)(pr + 160 + quad * 8);

        int e0 = rowptr[v], e1 = rowptr[v + 1];
        int deg = e1 - e0;
        float acc0[4][4], acc1[4][4], acc2[4][4];
#pragma unroll
        for (int blk = 0; blk < 4; blk++)
#pragma unroll
            for (int r = 0; r < 4; r++) {
                acc0[blk][r] = -3.0e38f; acc1[blk][r] = -3.0e38f; acc2[blk][r] = -3.0e38f;
            }

        int cnt1 = 0, cnt2 = 0;
        int vsh = quad * 4;
        int nbf = deg >> 4;                    // full 16-edge batches

        for (int bi = 0; bi < nbf; bi++) {
            int e = e0 + bi * 16 + m;
            int wrd = sorted[e];
            int srcm = wrd & 0xFFFF;
            int a = (wrd >> 16) & 3;
            const f16* qr = Qi + (size_t)srcm * 192;
            f16x8 q10 = *(const f16x8*)(qr + 0   + quad * 8);
            f16x8 q11 = *(const f16x8*)(qr + 32  + quad * 8);
            f16x8 q20 = *(const f16x8*)(qr + 64  + quad * 8);
            f16x8 q21 = *(const f16x8*)(qr + 96  + quad * 8);
            f16x8 q30 = *(const f16x8*)(qr + 128 + quad * 8);
            f16x8 q31 = *(const f16x8*)(qr + 160 + quad * 8);
            unsigned long long bl1 = __ballot(a >= 1);
            unsigned long long bl2 = __ballot(a <= 1);
            cnt1 += __popc((unsigned)bl1 & 0xFFFFu);
            cnt2 += __popc((unsigned)bl2 & 0xFFFFu);
            float am1[4], am2[4];
#pragma unroll
            for (int r = 0; r < 4; r++) {
                am1[r] = ((bl1 >> (vsh + r)) & 1) ? 0.f : -3.0e38f;
                am2[r] = ((bl2 >> (vsh + r)) & 1) ? 0.f : -3.0e38f;
            }
            // branch 3: all edges valid in full batch — plain fmax
            {
                f16x8 a0 = relupq(pl2, q30);
                f16x8 a1 = relupq(ph2, q31);
#pragma unroll
                for (int blk = 0; blk < 4; blk++) {
                    f32x4 c = { 0.f, 0.f, 0.f, 0.f };
                    c = __builtin_amdgcn_mfma_f32_16x16x32_f16(a0, wf3[blk][0], c, 0, 0, 0);
                    c = __builtin_amdgcn_mfma_f32_16x16x32_f16(a1, wf3[blk][1], c, 0, 0, 0);
#pragma unroll
                    for (int r = 0; r < 4; r++)
                        acc2[blk][r] = fmaxf(acc2[blk][r], c[r]);
                }
            }
            {
                f16x8 a0 = relupq(pl0, q10);
                f16x8 a1 = relupq(ph0, q11);
                ECV_BR_LDS(0, a0, a1, am1, acc0)
            }
            {
                f16x8 a0 = relupq(pl1, q20);
                f16x8 a1 = relupq(ph1, q21);
                ECV_BR_LDS(1, a0, a1, am2, acc1)
            }
        }

        if (deg & 15) {                        // tail batch
            int e = e0 + nbf * 16 + m;
            bool in = e < e1;
            int wrd = in ? sorted[e] : 0;
            int srcm = in ? (wrd & 0xFFFF) : v;
            int a = (wrd >> 16) & 3;
            bool mm1 = in && (a >= 1);
            bool mm2 = in && (a <= 1);
            const f16* qr = Qi + (size_t)srcm * 192;
            f16x8 q10 = *(const f16x8*)(qr + 0   + quad * 8);
            f16x8 q11 = *(const f16x8*)(qr + 32  + quad * 8);
            f16x8 q20 = *(const f16x8*)(qr + 64  + quad * 8);
            f16x8 q21 = *(const f16x8*)(qr + 96  + quad * 8);
            f16x8 q30 = *(const f16x8*)(qr + 128 + quad * 8);
            f16x8 q31 = *(const f16x8*)(qr + 160 + quad * 8);
            unsigned long long bl1 = __ballot(mm1);
            unsigned long long bl2 = __ballot(mm2);
            unsigned long long bl3 = __ballot(in);
            cnt1 += __popc((unsigned)bl1 & 0xFFFFu);
            cnt2 += __popc((unsigned)bl2 & 0xFFFFu);
            float am1[4], am2[4], am3[4];
#pragma unroll
            for (int r = 0; r < 4; r++) {
                am1[r] = ((bl1 >> (vsh + r)) & 1) ? 0.f : -3.0e38f;
                am2[r] = ((bl2 >> (vsh + r)) & 1) ? 0.f : -3.0e38f;
                am3[r] = ((bl3 >> (vsh + r)) & 1) ? 0.f : -3.0e38f;
            }
            {
                f16x8 a0 = relupq(pl2, q30);
                f16x8 a1 = relupq(ph2, q31);
#pragma unroll
                for (int blk = 0; blk < 4; blk++) {
                    f32x4 c = { 0.f, 0.f, 0.f, 0.f };
                    c = __builtin_amdgcn_mfma_f32_16x16x32_f16(a0, wf3[blk][0], c, 0, 0, 0);
                    c = __builtin_amdgcn_mfma_f32_16x16x32_f16(a1, wf3[blk][1], c, 0, 0, 0);
#pragma unroll
                    for (int r = 0; r < 4; r++)
                        acc2[blk][r] = fmaxf(acc2[blk][r], c[r] + am3[r]);
                }
            }
            if (bl1 & 0xFFFFull) {
                f16x8 a0 = relupq(pl0, q10);
                f16x8 a1 = relupq(ph0, q11);
                ECV_BR_LDS(0, a0, a1, am1, acc0)
            }
            if (bl2 & 0xFFFFull) {
                f16x8 a0 = relupq(pl1, q20);
                f16x8 a1 = relupq(ph1, q21);
                ECV_BR_LDS(1, a0, a1, am2, acc1)
            }
        }

        ECV_EPI(0, acc0, cnt1)
        ECV_EPI(1, acc1, cnt2)
        ECV_EPI(2, acc2, deg)
        if (lane == 0) {
            float4 ic;
            ic.x = 1.f / (float)(cnt1 > 0 ? cnt1 : 1);
            ic.y = 1.f / (float)(cnt2 > 0 ? cnt2 : 1);
            ic.z = 1.f / (float)(deg  > 0 ? deg  : 1);
            ic.w = 0.f;
            *(float4*)(invc4 + (size_t)v * 4) = ic;
        }
    }
}

// ---------- K6a: fused 3-branch mean aggregation; 8 lanes/edge, f16x8 loads ----------
__global__ __launch_bounds__(256) void k_agg_f(
    const int* __restrict__ rowptr, const int* __restrict__ sorted,
    const f16* __restrict__ y1i, const float* __restrict__ invc4,
    f16* __restrict__ aggi)
{
    int wid = threadIdx.x >> 6, lane = threadIdx.x & 63;
    int eslot = lane >> 3, cg = lane & 7;
    int gw = blockIdx.x * 4 + wid;
    for (int v = gw; v < NN; v += PWAVES) {
        int e0 = rowptr[v], e1 = rowptr[v + 1];
        float s1[8], s2[8], s3[8];
#pragma unroll
        for (int j = 0; j < 8; j++) { s1[j] = 0.f; s2[j] = 0.f; s3[j] = 0.f; }
        for (int eb = e0; eb < e1; eb += 8) {
            int e = eb + eslot;
            bool val = e < e1;
            int ec = val ? e : (e1 - 1);
            int w = sorted[ec];
            int src = w & 0xFFFF, a = (w >> 16) & 3;
            float f3 = val ? 1.f : 0.f;
            float f1 = (val && a >= 1) ? 1.f : 0.f;
            float f2 = (val && a <= 1) ? 1.f : 0.f;
            const f16* row = y1i + (size_t)src * 192 + cg * 8;
            f16x8 u1 = *(const f16x8*)(row);
            f16x8 u2 = *(const f16x8*)(row + 64);
            f16x8 u3 = *(const f16x8*)(row + 128);
#pragma unroll
            for (int j = 0; j < 8; j++) {
                s1[j] = fmaf(f1, (float)u1[j], s1[j]);
                s2[j] = fmaf(f2, (float)u2[j], s2[j]);
                s3[j] = fmaf(f3, (float)u3[j], s3[j]);
            }
        }
        // reduce across the 8 edge-slots (lane bits 3,4,5)
#pragma unroll
        for (int j = 0; j < 8; j++) {
            s1[j] += __shfl_xor(s1[j], 8);  s1[j] += __shfl_xor(s1[j], 16); s1[j] += __shfl_xor(s1[j], 32);
            s2[j] += __shfl_xor(s2[j], 8);  s2[j] += __shfl_xor(s2[j], 16); s2[j] += __shfl_xor(s2[j], 32);
            s3[j] += __shfl_xor(s3[j], 8);  s3[j] += __shfl_xor(s3[j], 16); s3[j] += __shfl_xor(s3[j], 32);
        }
        if (eslot == 0) {
            float4 icv = *(const float4*)(invc4 + (size_t)v * 4);
            f16* od = aggi + (size_t)v * 192 + cg * 8;
            f16x8 r1, r2, r3;
#pragma unroll
            for (int j = 0; j < 8; j++) {
                r1[j] = (f16)(s1[j] * icv.x);
                r2[j] = (f16)(s2[j] * icv.y);
                r3[j] = (f16)(s3[j] * icv.z);
            }
            *(f16x8*)(od)       = r1;
            *(f16x8*)(od + 64)  = r2;
            *(f16x8*)(od + 128) = r3;
        }
    }
}

// ---------- K6b: sage1 + fused proj (per branch) ----------
__global__ __launch_bounds__(256) void k_sage1(
    const f16* __restrict__ aggA, const f16* __restrict__ y1A,   // pre-offset by b*64, stride 192
    const float* __restrict__ WsageT, const float* __restrict__ bias21,
    const float* __restrict__ Wl3, const float* __restrict__ bl3,
    const float* __restrict__ Wr3,
    float* __restrict__ pz4, int b)
{
    __shared__ float wt[64 * 64];
    __shared__ float xt[128 * 68];
    __shared__ float wl[64], wr[64];
    int tid = threadIdx.x;
    int m0 = blockIdx.x * 128;
    int cg = tid & 15, rg = tid >> 4;
    if (tid < 64) { wl[tid] = Wl3[tid]; wr[tid] = Wr3[tid]; }
    float blv = bl3[0];
    float acc[8][4];
#pragma unroll
    for (int r = 0; r < 8; r++)
#pragma unroll
        for (int j = 0; j < 4; j++) acc[r][j] = 0.f;
    for (int ch = 0; ch < 2; ch++) {
        const f16* A = ch ? y1A : aggA;
        __syncthreads();
#pragma unroll
        for (int i = 0; i < 4; i++)
            ((float4*)wt)[i * 256 + tid] = ((const float4*)(WsageT + ch * 4096))[i * 256 + tid];
#pragma unroll
        for (int i = 0; i < 4; i++) {
            int li = i * 256 + tid;
            int rr = li >> 3, q = li & 7;
            int row = m0 + rr;
            f16x8 u = {};
            if (row < NN) u = *(const f16x8*)(A + (size_t)row * 192 + q * 8);
            float4 lo4 = make_float4((float)u[0], (float)u[1], (float)u[2], (float)u[3]);
            float4 hi4 = make_float4((float)u[4], (float)u[5], (float)u[6], (float)u[7]);
            *(float4*)(xt + rr * 68 + q * 8) = lo4;
            *(float4*)(xt + rr * 68 + q * 8 + 4) = hi4;
        }
        __syncthreads();
#pragma unroll 8
        for (int k = 0; k < 64; k++) {
            float4 wv = *(const float4*)(wt + k * 64 + cg * 4);
#pragma unroll
            for (int r = 0; r < 8; r++) {
                float xv = xt[(rg * 8 + r) * 68 + k];
                acc[r][0] += xv * wv.x; acc[r][1] += xv * wv.y;
                acc[r][2] += xv * wv.z; acc[r][3] += xv * wv.w;
            }
        }
    }
#pragma unroll
    for (int r = 0; r < 8; r++) {
        int row = m0 + rg * 8 + r;
        float ap = 0.f, az = 0.f;
#pragma unroll
        for (int j = 0; j < 4; j++) {
            float t = fmaxf(acc[r][j] + bias21[cg * 4 + j], 0.f);
            ap += t * wl[cg * 4 + j];
            az += t * wr[cg * 4 + j];
        }
        ap += __shfl_xor(ap, 1); ap += __shfl_xor(ap, 2);
        ap += __shfl_xor(ap, 4); ap += __shfl_xor(ap, 8);
        az += __shfl_xor(az, 1); az += __shfl_xor(az, 2);
        az += __shfl_xor(az, 4); az += __shfl_xor(az, 8);
        if (cg == 0 && row < NN) {
            pz4[(size_t)row * 4 + b] = ap;
            float zz = az + blv;
            if (b == 0) pz4[(size_t)row * 4 + 3] = zz;
            else        pz4[(size_t)row * 4 + 3] += zz;
        }
    }
}

// ---------- K8: fused 3-branch sage2 + sigmoid; persistent waves ----------
__global__ __launch_bounds__(256) void k_sage2_f(
    const int* __restrict__ rowptr, const int* __restrict__ sorted,
    const float* __restrict__ pz4, const float* __restrict__ invc4,
    float* __restrict__ outp)
{
    int wid = threadIdx.x >> 6, lane = threadIdx.x & 63;
    int gw = blockIdx.x * 4 + wid;
    for (int v = gw; v < NN; v += PWAVES) {
        int e0 = rowptr[v], e1 = rowptr[v + 1];
        float s1 = 0.f, s2 = 0.f, s3 = 0.f;
        for (int e = e0 + lane; e < e1; e += 64) {
            int w = sorted[e];
            int src = w & 0xFFFF, a = (w >> 16) & 3;
            float4 pz = *(const float4*)(pz4 + (size_t)src * 4);
            s3 += pz.z;
            if (a >= 1) s1 += pz.x;
            if (a <= 1) s2 += pz.y;
        }
#pragma unroll
        for (int off = 32; off > 0; off >>= 1) {
            s1 += __shfl_xor(s1, off);
            s2 += __shfl_xor(s2, off);
            s3 += __shfl_xor(s3, off);
        }
        if (lane == 0) {
            float4 icv = *(const float4*)(invc4 + (size_t)v * 4);
            float zsum = pz4[(size_t)v * 4 + 3];
            float val = s1 * icv.x + s2 * icv.y + s3 * icv.z + zsum;
            outp[v] = 1.f / (1.f + expf(-val));
        }
    }
}

// ---------- launch ----------
extern "C" void kernel_launch(void* const* d_in, const int* in_sizes, int n_in,
                              void* d_out, int out_size, void* d_ws, size_t ws_size,
                              hipStream_t stream)
{
    const float* x    = (const float*)d_in[0];
    const int* ei     = (const int*)d_in[1];
    const int* attr   = (const int*)d_in[2];
    const float* Wspf = (const float*)d_in[3];
    const float* bspf = (const float*)d_in[4];
    const float* W011 = (const float*)d_in[5];
    const float* b011 = (const float*)d_in[6];
    const float* W012 = (const float*)d_in[7];
    const float* b012 = (const float*)d_in[8];
    const float* bn01 = (const float*)d_in[9];
    const float* eW1[3] = { (const float*)d_in[10], (const float*)d_in[15], (const float*)d_in[20] };
    const float* eb1[3] = { (const float*)d_in[11], (const float*)d_in[16], (const float*)d_in[21] };
    const float* eW2[3] = { (const float*)d_in[12], (const float*)d_in[17], (const float*)d_in[22] };
    const float* eb2[3] = { (const float*)d_in[13], (const float*)d_in[18], (const float*)d_in[23] };
    const float* bn1[3] = { (const float*)d_in[14], (const float*)d_in[19], (const float*)d_in[24] };
    const float* s21Wl = (const float*)d_in[25];
    const float* s21bl = (const float*)d_in[26];
    const float* s21Wr = (const float*)d_in[27];
    const float* bn21  = (const float*)d_in[28];
    const float* s3Wl[3] = { (const float*)d_in[29], (const float*)d_in[32], (const float*)d_in[35] };
    const float* s3bl[3] = { (const float*)d_in[30], (const float*)d_in[33], (const float*)d_in[36] };
    const float* s3Wr[3] = { (const float*)d_in[31], (const float*)d_in[34], (const float*)d_in[37] };

    char* ws = (char*)d_ws;
    unsigned short* Whl = (unsigned short*)(ws + OFF_WHL);
    float* WspP   = (float*)(ws + OFF_WSPP);
    float* bias01 = (float*)(ws + OFF_BIAS01);
    float* W1pqT  = (float*)(ws + OFF_W1PQT);
    float* biasPQ = (float*)(ws + OFF_BIASPQ);
    float* WsageT = (float*)(ws + OFF_WSAGET);
    float* bias21 = (float*)(ws + OFF_BIAS21);
    float* bnf    = (float*)(ws + OFF_BNF);
    f16*   W2h    = (f16*)(ws + OFF_W2BF);
    float* invc4  = (float*)(ws + OFF_INVC4);
    float* pz4    = (float*)(ws + OFF_PZ4);
    int*   rp     = (int*)(ws + OFF_RP);
    int*   parts  = (int*)(ws + OFF_PARTS);
    int*   deg    = (int*)(ws + OFF_DEG);
    int*   ghead  = (int*)(ws + OFF_GHEAD);
    int*   sorted = (int*)(ws + OFF_SORT);
    unsigned int* ebuck = (unsigned int*)(ws + OFF_EBUCK);
    float* h      = (float*)(ws + OFF_H);
    f16*   Pi     = (f16*)(ws + OFF_PI);
    f16*   Qi     = (f16*)(ws + OFF_QI);
    f16*   y1i    = (f16*)(ws + OFF_Y1I);
    f16*   aggi   = (f16*)(ws + OFF_AGGI);   // overlays Pi (dead after edgeconv)

    hipMemsetAsync(ws + OFF_DEG, 0, 200064, stream);

    k_prep<<<689, 256, 0, stream>>>(
        Wspf, bspf, W011, b011, W012, b012, bn01,
        eW1[0], eb1[0], eb2[0], bn1[0],
        eW1[1], eb1[1], eb2[1], bn1[1],
        eW1[2], eb1[2], eb2[2], bn1[2],
        eW2[0], eW2[1], eW2[2],
        s21Wl, s21bl, s21Wr, bn21,
        Whl, WspP, bias01, W1pqT, biasPQ, WsageT, bias21, bnf, W2h);

    k_hist<<<3907, 256, 0, stream>>>(ei + EE, deg);
    k_psum<<<NBK, 256, 0, stream>>>(deg, parts);
    k_pscan<<<1, 256, 0, stream>>>(parts);
    k_scanfix<<<NBK, 256, 0, stream>>>(deg, parts, rp);
    k_gheadinit<<<1, 256, 0, stream>>>(rp, ghead);
    k_bucketA<<<245, 256, 0, stream>>>(ei, ei + EE, attr, ghead, ebuck);
    k_bucketB<<<NBK, 256, 0, stream>>>(rp, ebuck, sorted);

    k_h<<<3125, 256, 0, stream>>>(x, Whl, WspP, bias01, h);

    k_pq<<<782, 256, 0, stream>>>(h, W1pqT, biasPQ, Pi, Qi);

    k_edgeconv_f<<<PWAVES / 4, 256, 0, stream>>>(rp, sorted, Pi, Qi, W2h, bnf, y1i, invc4);
    k_agg_f<<<PWAVES / 4, 256, 0, stream>>>(rp, sorted, y1i, invc4, aggi);

    for (int b = 0; b < 3; b++)
        k_sage1<<<391, 256, 0, stream>>>(aggi + b * 64, y1i + b * 64, WsageT, bias21,
                                         s3Wl[b], s3bl[b], s3Wr[b], pz4, b);

    k_sage2_f<<<PWAVES / 4, 256, 0, stream>>>(rp, sorted, pz4, invc4, (float*)d_out);
}

// Round 6
// 770.229 us; speedup vs baseline: 1.1344x; 1.1344x over previous
//
#include <hip/hip_runtime.h>
#include <cstdint>
#include <cstddef>

#define NN 50000
#define EE 1000000
#define NBK 196          // dst buckets (dst>>8), 196*256 = 50176 >= NN
#define PWAVES 5120      // persistent waves for gather kernels (1280 blocks * 4)

typedef __attribute__((ext_vector_type(8))) short bf16x8;
typedef __attribute__((ext_vector_type(4))) short s16x4;
typedef __attribute__((ext_vector_type(4))) float f32x4;
typedef _Float16 f16;
typedef __attribute__((ext_vector_type(2))) _Float16 f16x2;
typedef __attribute__((ext_vector_type(4))) _Float16 f16x4;
typedef __attribute__((ext_vector_type(8))) _Float16 f16x8;

// truncation split: v == bf16(hi) + ~bf16(lo), residual ~2^-16 rel
__device__ __forceinline__ void split2(float v, short& hi, short& lo) {
    union { float f; unsigned int u; } a; a.f = v;
    unsigned short h16 = (unsigned short)(a.u >> 16);
    union { unsigned int u; float f; } hf; hf.u = ((unsigned int)h16) << 16;
    union { float f; unsigned int u; } b; b.f = v - hf.f;
    hi = (short)h16;
    lo = (short)(b.u >> 16);
}

// relu(p+q) in packed f16 (v_pk_add_f16 + v_pk_max_f16)
__device__ __forceinline__ f16x8 relupq(f16x8 p, f16x8 q) {
    f16x8 s = p + q;
    f16x8 z = {};
#if __has_builtin(__builtin_elementwise_max)
    return __builtin_elementwise_max(s, z);
#else
    f16x8 r;
#pragma unroll
    for (int j = 0; j < 8; j++) r[j] = (s[j] > (f16)0.f) ? s[j] : (f16)0.f;
    return r;
#endif
}

// ---------- workspace layout (byte offsets) ----------
#define OFF_WHL    ((size_t)0)          // 2*1024*64 bf16 = 262144
#define OFF_WSPP   ((size_t)262144)     // 64*4 f32
#define OFF_BIAS01 ((size_t)263168)     // 64 f32
#define OFF_W1PQT  ((size_t)263424)     // 3*64*128 f32
#define OFF_BIASPQ ((size_t)361728)     // 3*128 f32
#define OFF_WSAGET ((size_t)363264)     // 128*64 f32
#define OFF_BIAS21 ((size_t)396032)     // 64 f32
#define OFF_BNF    ((size_t)396288)     // 3*192 f32 (+pad to 2560)
#define OFF_W2BF   ((size_t)398848)     // 3*64*64 f16 = 24576
#define OFF_INVC4  ((size_t)423424)     // N*4 f32 = 800000 {ic1,ic2,ic3,0}
#define OFF_PZ4    ((size_t)1223424)    // N*4 f32 = 800000 {p1,p2,p3,zsum}
#define OFF_RP     ((size_t)2023424)    // (NN+1) i32 (+pad 200064)
#define OFF_PARTS  ((size_t)2223488)    // 256 i32 (+pad 4096)
#define OFF_DEG    ((size_t)2227584)    // N i32 (+pad 200064)
#define OFF_GHEAD  ((size_t)2427648)    // NBK i32 (+pad 4096)
#define OFF_SORT   ((size_t)2431744)    // E i32 = 4000000 (src | attr<<16)
#define OFF_H      ((size_t)6431744)    // N*64 f32 = 12800000
#define OFF_PI     ((size_t)19231744)   // N*192 f16 = 19200000 (P, interleaved 3 branches)
#define OFF_QI     ((size_t)38431744)   // N*192 f16 = 19200000 (Q, interleaved)
#define OFF_Y1I    ((size_t)57631744)   // N*192 f16 = 19200000 (end 76831744)
#define OFF_EBUCK  OFF_H                // overlay: E u32, dead before k_h
#define OFF_AGGI   OFF_PI               // overlay: N*192 f16, Pi dead after edgeconv

// ---------- K1: weight prep / folding ----------
__global__ __launch_bounds__(256) void k_prep(
    const float* __restrict__ Wspf, const float* __restrict__ bspf,
    const float* __restrict__ W011, const float* __restrict__ b011,
    const float* __restrict__ W012, const float* __restrict__ b012,
    const float* __restrict__ bn01,
    const float* __restrict__ e1W1, const float* __restrict__ e1b1,
    const float* __restrict__ e1b2, const float* __restrict__ bn11,
    const float* __restrict__ e2W1, const float* __restrict__ e2b1,
    const float* __restrict__ e2b2, const float* __restrict__ bn12,
    const float* __restrict__ e3W1, const float* __restrict__ e3b1,
    const float* __restrict__ e3b2, const float* __restrict__ bn13,
    const float* __restrict__ e1W2, const float* __restrict__ e2W2,
    const float* __restrict__ e3W2,
    const float* __restrict__ s21Wl, const float* __restrict__ s21bl,
    const float* __restrict__ s21Wr, const float* __restrict__ bn21,
    unsigned short* __restrict__ Whl, float* __restrict__ WspP, float* __restrict__ bias01,
    float* __restrict__ W1pqT, float* __restrict__ biasPQ,
    float* __restrict__ WsageT, float* __restrict__ bias21, float* __restrict__ bnf,
    f16* __restrict__ W2h)
{
    int idx = blockIdx.x * 256 + threadIdx.x;
    if (idx < 131072) {
        int hl = idx >> 16;
        int r = idx & 65535;
        int kchunk = r >> 11;
        int r2 = r & 2047;
        int blk = r2 >> 9;
        int r3 = r2 & 511;
        int lane = r3 >> 3;
        int j = r3 & 7;
        int n = lane & 15, quad = lane >> 4;
        int k = kchunk * 32 + quad * 8 + j;
        int c = blk * 16 + n;
        float s = bn01[c] * rsqrtf(bn01[192 + c] + 1e-5f);
        float w = ((k < 512) ? W012[c * 512 + k] : W011[c * 576 + (k - 512)]) * s;
        short hi, lo;
        split2(w, hi, lo);
        Whl[idx] = (unsigned short)(hl ? lo : hi);
    } else if (idx < 131072 + 24576) {
        int r = idx - 131072;
        int b = r >> 13; r &= 8191;
        int k = r >> 7, cp = r & 127;
        const float* W1 = (b == 0) ? e1W1 : (b == 1) ? e2W1 : e3W1;
        float val;
        if (cp < 64) val = W1[cp * 128 + k] - W1[cp * 128 + 64 + k];
        else         val = W1[(cp - 64) * 128 + 64 + k];
        W1pqT[b * 8192 + k * 128 + cp] = val;
    } else if (idx < 131072 + 24576 + 8192) {
        int r = idx - (131072 + 24576);
        int k = r >> 6, c = r & 63;
        float s = bn21[c] * rsqrtf(bn21[192 + c] + 1e-5f);
        float w = (k < 64) ? s21Wl[c * 64 + k] : s21Wr[c * 64 + (k - 64)];
        WsageT[k * 64 + c] = w * s;
    } else if (idx < 131072 + 24576 + 8192 + 64) {
        int c = idx - (131072 + 24576 + 8192);
        float s01 = bn01[c] * rsqrtf(bn01[192 + c] + 1e-5f);
        float wsp0 = 0.f, wsp1 = 0.f, wsp2 = 0.f, wsp3 = 0.f, bacc = 0.f;
        for (int j = 0; j < 64; j++) {
            float w = W011[c * 576 + 512 + j];
            wsp0 += w * Wspf[j * 4 + 0];
            wsp1 += w * Wspf[j * 4 + 1];
            wsp2 += w * Wspf[j * 4 + 2];
            wsp3 += w * Wspf[j * 4 + 3];
            bacc += w * bspf[j];
        }
        WspP[c * 4 + 0] = wsp0 * s01; WspP[c * 4 + 1] = wsp1 * s01;
        WspP[c * 4 + 2] = wsp2 * s01; WspP[c * 4 + 3] = wsp3 * s01;
        bias01[c] = (b011[c] + b012[c] + bacc) * s01 + (bn01[64 + c] - bn01[128 + c] * s01);
        float s21 = bn21[c] * rsqrtf(bn21[192 + c] + 1e-5f);
        bias21[c] = s21bl[c] * s21 + (bn21[64 + c] - bn21[128 + c] * s21);
        const float* b1a[3] = { e1b1, e2b1, e3b1 };
        const float* b2a[3] = { e1b2, e2b2, e3b2 };
        const float* bna[3] = { bn11, bn12, bn13 };
#pragma unroll
        for (int b = 0; b < 3; b++) {
            float s = bna[b][c] * rsqrtf(bna[b][192 + c] + 1e-5f);
            float tr = bna[b][64 + c] - bna[b][128 + c] * s;
            bnf[b * 192 + c] = s;
            bnf[b * 192 + 64 + c] = b2a[b][c] * s + tr;
            bnf[b * 192 + 128 + c] = tr;
            biasPQ[b * 128 + c] = b1a[b][c];
            biasPQ[b * 128 + 64 + c] = 0.f;
        }
    } else if (idx < 131072 + 24576 + 8192 + 64 + 12288) {
        int r = idx - (131072 + 24576 + 8192 + 64);
        int b = r >> 12, i = r & 4095;
        const float* W2 = (b == 0) ? e1W2 : (b == 1) ? e2W2 : e3W2;
        W2h[b * 4096 + i] = (f16)W2[i];
    }
}

// ---------- degree histogram (single, all edges) ----------
__global__ __launch_bounds__(256) void k_hist(
    const int* __restrict__ dst, int* __restrict__ deg)
{
    int e = blockIdx.x * 256 + threadIdx.x;
    if (e < EE) atomicAdd(&deg[dst[e]], 1);
}

__global__ __launch_bounds__(256) void k_psum(const int* __restrict__ deg, int* __restrict__ parts)
{
    int i = blockIdx.x * 256 + threadIdx.x;
    int v = (i < NN) ? deg[i] : 0;
#pragma unroll
    for (int off = 32; off > 0; off >>= 1) v += __shfl_xor(v, off);
    __shared__ int ws4[4];
    int wid = threadIdx.x >> 6;
    if ((threadIdx.x & 63) == 0) ws4[wid] = v;
    __syncthreads();
    if (threadIdx.x == 0)
        parts[blockIdx.x] = ws4[0] + ws4[1] + ws4[2] + ws4[3];
}

__global__ __launch_bounds__(256) void k_pscan(int* __restrict__ parts)
{
    __shared__ int sbuf[256];
    int tid = threadIdx.x;
    int v = (tid < NBK) ? parts[tid] : 0;
    sbuf[tid] = v;
    __syncthreads();
    for (int off = 1; off < 256; off <<= 1) {
        int t = (tid >= off) ? sbuf[tid - off] : 0;
        __syncthreads();
        sbuf[tid] += t;
        __syncthreads();
    }
    if (tid < NBK) parts[tid] = sbuf[tid] - v;  // exclusive
}

__global__ __launch_bounds__(256) void k_scanfix(
    const int* __restrict__ deg, const int* __restrict__ parts, int* __restrict__ rowptr)
{
    __shared__ int sbuf[256];
    int tid = threadIdx.x;
    int i = blockIdx.x * 256 + tid;
    int v = (i < NN) ? deg[i] : 0;
    sbuf[tid] = v;
    __syncthreads();
    for (int off = 1; off < 256; off <<= 1) {
        int t = (tid >= off) ? sbuf[tid - off] : 0;
        __syncthreads();
        sbuf[tid] += t;
        __syncthreads();
    }
    int base = parts[blockIdx.x];
    if (i < NN)      rowptr[i] = base + sbuf[tid] - v;
    if (i == NN - 1) rowptr[NN] = base + sbuf[tid];
}

__global__ __launch_bounds__(256) void k_gheadinit(
    const int* __restrict__ rp, int* __restrict__ ghead)
{
    int t = threadIdx.x;
    if (t < NBK) ghead[t] = rp[t * 256];
}

// ---------- bucketed sort pass A: partition edges into dst-buckets ----------
__global__ __launch_bounds__(256) void k_bucketA(
    const int* __restrict__ src, const int* __restrict__ dst, const int* __restrict__ attr,
    int* __restrict__ ghead, unsigned int* __restrict__ ebuck)
{
    __shared__ int hist[NBK];
    __shared__ int head[NBK];
    int tid = threadIdx.x;
    if (tid < NBK) hist[tid] = 0;
    __syncthreads();
    int base_e = blockIdx.x * 4096;
    unsigned int word[16]; int bkt[16];
#pragma unroll
    for (int k = 0; k < 16; k++) {
        int e = base_e + k * 256 + tid;
        if (e < EE) {
            int d = dst[e], s = src[e], a = attr[e] + 1;
            int b = d >> 8;
            word[k] = (unsigned)s | ((unsigned)a << 16) | ((unsigned)(d & 255) << 18);
            bkt[k] = b;
            atomicAdd(&hist[b], 1);
        } else { bkt[k] = -1; word[k] = 0; }
    }
    __syncthreads();
    if (tid < NBK) {
        int c = hist[tid];
        head[tid] = c ? atomicAdd(&ghead[tid], c) : 0;
    }
    __syncthreads();
#pragma unroll
    for (int k = 0; k < 16; k++) {
        if (bkt[k] >= 0) {
            int pos = atomicAdd(&head[bkt[k]], 1);
            ebuck[pos] = word[k];
        }
    }
}

// ---------- bucketed sort pass B: exact dst sort within bucket ----------
__global__ __launch_bounds__(256) void k_bucketB(
    const int* __restrict__ rp, const unsigned int* __restrict__ ebuck,
    int* __restrict__ sorted)
{
    __shared__ int sbuf[256];
    __shared__ int head[256];
    int b = blockIdx.x, tid = threadIdx.x;
    int n0 = b * 256;
    int n1 = n0 + 256; if (n1 > NN) n1 = NN;
    int r0 = rp[n0];
    int r1 = rp[n1];
    sbuf[tid] = 0;
    __syncthreads();
    for (int e = r0 + tid; e < r1; e += 256)
        atomicAdd(&sbuf[(ebuck[e] >> 18) & 255], 1);
    __syncthreads();
    int v = sbuf[tid];
    for (int off = 1; off < 256; off <<= 1) {
        int t = (tid >= off) ? sbuf[tid - off] : 0;
        __syncthreads();
        sbuf[tid] += t;
        __syncthreads();
    }
    head[tid] = r0 + sbuf[tid] - v;
    __syncthreads();
    for (int e = r0 + tid; e < r1; e += 256) {
        unsigned int w = ebuck[e];
        int pos = atomicAdd(&head[(w >> 18) & 255], 1);
        sorted[pos] = (int)(w & 0x3FFFFu);   // src | attr<<16
    }
}

// ---------- K2: h = relu(fold_bn01(x @ Wc')) ----------
__global__ __launch_bounds__(256) void k_h(
    const float* __restrict__ x, const unsigned short* __restrict__ Whl,
    const float* __restrict__ WspP, const float* __restrict__ bias01,
    float* __restrict__ h)
{
    __shared__ unsigned short hib[2][4096];
    __shared__ unsigned short lob[2][4096];
    int tid = threadIdx.x;
    int w = tid >> 6, l = tid & 63;
    int tile = blockIdx.x;
    int m = l & 15, quad = l >> 4;
    int blk = w;
    const unsigned short* Wh = Whl;
    const unsigned short* Wl = Whl + 65536;
    const size_t xbase = (size_t)tile * 16 * 1028;

    int oct_w = l >> 1, off_w = (l & 1) * 4;

    f32x4 g[4];
#pragma unroll
    for (int p = 0; p < 4; p++)
        g[p] = *(const f32x4*)(x + xbase + (size_t)(p * 4 + w) * 1028 + l * 4);
#pragma unroll
    for (int p = 0; p < 4; p++) {
        int r = p * 4 + w;
        int op = r * 256 + (oct_w ^ (r & 7)) * 8 + off_w;
        s16x4 h4, l4;
#pragma unroll
        for (int i = 0; i < 4; i++) { short hi, lo; split2(g[p][i], hi, lo); h4[i] = hi; l4[i] = lo; }
        *(s16x4*)(&hib[0][op]) = h4;
        *(s16x4*)(&lob[0][op]) = l4;
    }
    __syncthreads();

    f32x4 acc = { 0.f, 0.f, 0.f, 0.f };
    for (int c = 0; c < 4; c++) {
        if (c < 3) {
#pragma unroll
            for (int p = 0; p < 4; p++)
                g[p] = *(const f32x4*)(x + xbase + (size_t)(p * 4 + w) * 1028 + (c + 1) * 256 + l * 4);
        }
        int buf = c & 1;
        const unsigned short* hp = &hib[buf][m * 256];
        const unsigned short* lp = &lob[buf][m * 256];
        int msw = m & 7;
#pragma unroll
        for (int ks = 0; ks < 8; ks++) {
            int oct = ks * 4 + quad;
            int ao = (oct ^ msw) * 8;
            bf16x8 xh = *(const bf16x8*)(hp + ao);
            bf16x8 xl = *(const bf16x8*)(lp + ao);
            int fb = (c * 8 + ks) * 2048 + blk * 512 + l * 8;
            bf16x8 bh = *(const bf16x8*)(Wh + fb);
            bf16x8 bl = *(const bf16x8*)(Wl + fb);
            acc = __builtin_amdgcn_mfma_f32_16x16x32_bf16(xh, bh, acc, 0, 0, 0);
            acc = __builtin_amdgcn_mfma_f32_16x16x32_bf16(xl, bh, acc, 0, 0, 0);
            acc = __builtin_amdgcn_mfma_f32_16x16x32_bf16(xh, bl, acc, 0, 0, 0);
        }
        if (c < 3) {
            int nbuf = (c + 1) & 1;
#pragma unroll
            for (int p = 0; p < 4; p++) {
                int r = p * 4 + w;
                int op = r * 256 + (oct_w ^ (r & 7)) * 8 + off_w;
                s16x4 h4, l4;
#pragma unroll
                for (int i = 0; i < 4; i++) { short hi, lo; split2(g[p][i], hi, lo); h4[i] = hi; l4[i] = lo; }
                *(s16x4*)(&hib[nbuf][op]) = h4;
                *(s16x4*)(&lob[nbuf][op]) = l4;
            }
            __syncthreads();
        }
    }

    int ch = blk * 16 + m;
    f32x4 wsp = *(const f32x4*)(WspP + ch * 4);
    float bia = bias01[ch];
#pragma unroll
    for (int r = 0; r < 4; r++) {
        int row = tile * 16 + quad * 4 + r;
        f32x4 sp = *(const f32x4*)(x + (size_t)row * 1028 + 1024);
        float a = acc[r] + sp[0] * wsp[0] + sp[1] * wsp[1]
                + sp[2] * wsp[2] + sp[3] * wsp[3] + bia;
        h[(size_t)row * 64 + ch] = fmaxf(a, 0.f);
    }
}

// ---------- K4: all 3 branches fused: P = h @ W1p' + b1 (f16), Q = h @ W1q' (f16) ----------
__global__ __launch_bounds__(256) void k_pq(
    const float* __restrict__ h, const float* __restrict__ WT3,
    const float* __restrict__ biasPQ, f16* __restrict__ Pi, f16* __restrict__ Qi)
{
    __shared__ float wt[64 * 128];
    __shared__ float xt[64 * 68];
    int tid = threadIdx.x;
    int m0 = blockIdx.x * 64;
    int cg = tid & 31, rg = tid >> 5;
#pragma unroll
    for (int i = 0; i < 4; i++) {
        int li = i * 256 + tid;
        int rr = li >> 4, q = li & 15;
        int row = m0 + rr;
        float4 u = make_float4(0.f, 0.f, 0.f, 0.f);
        if (row < NN) u = *(const float4*)(h + (size_t)row * 64 + q * 4);
        *(float4*)(xt + rr * 68 + q * 4) = u;
    }
    for (int b = 0; b < 3; b++) {
        __syncthreads();
#pragma unroll
        for (int i = 0; i < 8; i++)
            ((float4*)wt)[i * 256 + tid] = ((const float4*)(WT3 + b * 8192))[i * 256 + tid];
        __syncthreads();
        float acc[8][4];
#pragma unroll
        for (int r = 0; r < 8; r++)
#pragma unroll
            for (int j = 0; j < 4; j++) acc[r][j] = 0.f;
#pragma unroll 8
        for (int k = 0; k < 64; k++) {
            float4 wv = *(const float4*)(wt + k * 128 + cg * 4);
#pragma unroll
            for (int r = 0; r < 8; r++) {
                float xv = xt[(rg * 8 + r) * 68 + k];
                acc[r][0] += xv * wv.x; acc[r][1] += xv * wv.y;
                acc[r][2] += xv * wv.z; acc[r][3] += xv * wv.w;
            }
        }
        const float* biasP = biasPQ + b * 128;
#pragma unroll
        for (int r = 0; r < 8; r++) {
            int row = m0 + rg * 8 + r;
            if (row < NN) {
                if (cg < 16) {               // P half (+bias), fp16
                    f16x4 res;
#pragma unroll
                    for (int j = 0; j < 4; j++)
                        res[j] = (f16)(acc[r][j] + biasP[cg * 4 + j]);
                    *(f16x4*)(Pi + (size_t)row * 192 + b * 64 + cg * 4) = res;
                } else {                     // Q half, fp16
                    f16x4 res;
#pragma unroll
                    for (int j = 0; j < 4; j++)
                        res[j] = (f16)acc[r][j];
                    *(f16x4*)(Qi + (size_t)row * 192 + b * 64 + (cg - 16) * 4) = res;
                }
            }
        }
    }
}

// per-branch batch body: packed-f16 A-fragment, f16 MFMA, W2 frags from LDS (all 3 branches)
#define ECV_LDS_BRANCH(B, PL, PH, Q0, Q1, MASK, ACC)                               \
    if ((MASK) & 0xFFFFull) {                                                      \
        f16x8 a0 = relupq(PL, Q0);                                                 \
        f16x8 a1 = relupq(PH, Q1);                                                 \
        _Pragma("unroll") for (int blk = 0; blk < 4; blk++) {                      \
            f32x4 c = { 0.f, 0.f, 0.f, 0.f };                                      \
            f16x8 w0 = *(const f16x8*)(w2s + ((B) * 8 + blk * 2 + 0) * 512 + quad * 128 + m * 8); \
            f16x8 w1 = *(const f16x8*)(w2s + ((B) * 8 + blk * 2 + 1) * 512 + quad * 128 + m * 8); \
            c = __builtin_amdgcn_mfma_f32_16x16x32_f16(a0, w0, c, 0, 0, 0);        \
            c = __builtin_amdgcn_mfma_f32_16x16x32_f16(a1, w1, c, 0, 0, 0);        \
            _Pragma("unroll") for (int r = 0; r < 4; r++)                          \
                if (((MASK) >> (vsh + r)) & 1)                                     \
                    ACC[blk][r] = fmaxf(ACC[blk][r], c[r]);                        \
        }                                                                          \
    }

#define ECV_EPI(B, ACC, CNT)                                                       \
    {                                                                              \
        float red[4];                                                              \
        _Pragma("unroll") for (int blk = 0; blk < 4; blk++) {                      \
            float rv = fmaxf(fmaxf(ACC[blk][0], ACC[blk][1]),                      \
                             fmaxf(ACC[blk][2], ACC[blk][3]));                     \
            rv = fmaxf(rv, __shfl_xor(rv, 16));                                    \
            rv = fmaxf(rv, __shfl_xor(rv, 32));                                    \
            red[blk] = rv;                                                         \
        }                                                                          \
        float mx = red[quad];                                                      \
        const float* scb = bnf + (B) * 192;                                        \
        float outv = ((CNT) > 0) ? fmaxf(fmaf(mx, scb[lane], scb[64 + lane]), 0.f) \
                                 : fmaxf(scb[128 + lane], 0.f);                    \
        y1i[(size_t)v * 192 + (B) * 64 + lane] = (f16)outv;                        \
    }

// ---------- K5: fused 3-branch EdgeConv; persistent waves; all W2 in LDS ----------
__global__ __launch_bounds__(256) void k_edgeconv_f(
    const int* __restrict__ rowptr, const int* __restrict__ sorted,
    const f16* __restrict__ Pi, const f16* __restrict__ Qi,
    const f16* __restrict__ W2h,               // 3*64*64 f16
    const float* __restrict__ bnf,             // 3*192
    f16* __restrict__ y1i, float* __restrict__ invc4)
{
    __shared__ f16 w2s[12288];                 // 3 branches : 24 frags * 512 halves, bank-permuted
    int tid = threadIdx.x;
#pragma unroll
    for (int u0 = 0; u0 < 6; u0++) {
        int u = u0 * 256 + tid;                // 0..1535
        int frag = u >> 6;                     // b*8 + blk*2 + kc   (b in {0,1,2})
        int rem = u & 63;
        int m2 = rem >> 2, qd = rem & 3;
        int bb = frag >> 3, blk = (frag >> 1) & 3, kc = frag & 1;
        *(int4*)(w2s + frag * 512 + qd * 128 + m2 * 8) =
            *(const int4*)(W2h + (bb * 64 + blk * 16 + m2) * 64 + kc * 32 + qd * 8);
    }
    __syncthreads();

    int wid = tid >> 6, lane = tid & 63;
    int m = lane & 15, quad = lane >> 4;
    int gw = blockIdx.x * 4 + wid;             // persistent wave id, PWAVES total

    for (int v = gw; v < NN; v += PWAVES) {
        const f16* pr = Pi + (size_t)v * 192;
        f16x8 pl0 = *(const f16x8*)(pr + 0   + quad * 8);
        f16x8 ph0 = *(const f16x8*)(pr + 32  + quad * 8);
        f16x8 pl1 = *(const f16x8*)(pr + 64  + quad * 8);
        f16x8 ph1 = *(const f16x8*)(pr + 96  + quad * 8);
        f16x8 pl2 = *(const f16x8*)(pr + 128 + quad * 8);
        f16x8 ph2 = *(const f16x8*)(pr + 160 + quad * 8);

        int e0 = rowptr[v], e1 = rowptr[v + 1];
        int deg = e1 - e0;
        float acc0[4][4], acc1[4][4], acc2[4][4];
#pragma unroll
        for (int blk = 0; blk < 4; blk++)
#pragma unroll
            for (int r = 0; r < 4; r++) {
                acc0[blk][r] = -3.0e38f; acc1[blk][r] = -3.0e38f; acc2[blk][r] = -3.0e38f;
            }

        int cnt1 = 0, cnt2 = 0;
        int vsh = quad * 4;
        int nb = (deg + 15) >> 4;
        for (int bi = 0; bi < nb; bi++) {
            int e = e0 + bi * 16 + m;
            bool in = e < e1;
            int wrd = in ? sorted[e] : 0;
            int srcm = in ? (wrd & 0xFFFF) : v;
            int a = (wrd >> 16) & 3;
            bool mm1 = in && (a >= 1);
            bool mm2 = in && (a <= 1);
            const f16* qr = Qi + (size_t)srcm * 192;
            f16x8 q30 = *(const f16x8*)(qr + 128 + quad * 8);
            f16x8 q31 = *(const f16x8*)(qr + 160 + quad * 8);
            f16x8 q10 = {}, q11 = {}, q20 = {}, q21 = {};
            if (mm1) { q10 = *(const f16x8*)(qr + quad * 8);      q11 = *(const f16x8*)(qr + 32 + quad * 8); }
            if (mm2) { q20 = *(const f16x8*)(qr + 64 + quad * 8); q21 = *(const f16x8*)(qr + 96 + quad * 8); }
            unsigned long long bl1 = __ballot(mm1);
            unsigned long long bl2 = __ballot(mm2);
            unsigned long long bl3 = __ballot(in);
            cnt1 += __popc((unsigned)bl1 & 0xFFFFu);
            cnt2 += __popc((unsigned)bl2 & 0xFFFFu);

            ECV_LDS_BRANCH(2, pl2, ph2, q30, q31, bl3, acc2)
            ECV_LDS_BRANCH(0, pl0, ph0, q10, q11, bl1, acc0)
            ECV_LDS_BRANCH(1, pl1, ph1, q20, q21, bl2, acc1)
        }

        ECV_EPI(0, acc0, cnt1)
        ECV_EPI(1, acc1, cnt2)
        ECV_EPI(2, acc2, deg)
        if (lane == 0) {
            float4 ic;
            ic.x = 1.f / (float)(cnt1 > 0 ? cnt1 : 1);
            ic.y = 1.f / (float)(cnt2 > 0 ? cnt2 : 1);
            ic.z = 1.f / (float)(deg  > 0 ? deg  : 1);
            ic.w = 0.f;
            *(float4*)(invc4 + (size_t)v * 4) = ic;
        }
    }
}

// ---------- K6a: fused 3-branch mean aggregation; 8 lanes/edge, f16x8 loads ----------
__global__ __launch_bounds__(256) void k_agg_f(
    const int* __restrict__ rowptr, const int* __restrict__ sorted,
    const f16* __restrict__ y1i, const float* __restrict__ invc4,
    f16* __restrict__ aggi)
{
    int wid = threadIdx.x >> 6, lane = threadIdx.x & 63;
    int eslot = lane >> 3, cg = lane & 7;
    int gw = blockIdx.x * 4 + wid;
    for (int v = gw; v < NN; v += PWAVES) {
        int e0 = rowptr[v], e1 = rowptr[v + 1];
        float s1[8], s2[8], s3[8];
#pragma unroll
        for (int j = 0; j < 8; j++) { s1[j] = 0.f; s2[j] = 0.f; s3[j] = 0.f; }
        for (int eb = e0; eb < e1; eb += 8) {
            int e = eb + eslot;
            bool val = e < e1;
            int ec = val ? e : (e1 - 1);
            int w = sorted[ec];
            int src = w & 0xFFFF, a = (w >> 16) & 3;
            float f3 = val ? 1.f : 0.f;
            float f1 = (val && a >= 1) ? 1.f : 0.f;
            float f2 = (val && a <= 1) ? 1.f : 0.f;
            const f16* row = y1i + (size_t)src * 192 + cg * 8;
            f16x8 u1 = *(const f16x8*)(row);
            f16x8 u2 = *(const f16x8*)(row + 64);
            f16x8 u3 = *(const f16x8*)(row + 128);
#pragma unroll
            for (int j = 0; j < 8; j++) {
                s1[j] = fmaf(f1, (float)u1[j], s1[j]);
                s2[j] = fmaf(f2, (float)u2[j], s2[j]);
                s3[j] = fmaf(f3, (float)u3[j], s3[j]);
            }
        }
        // reduce across the 8 edge-slots (lane bits 3,4,5)
#pragma unroll
        for (int j = 0; j < 8; j++) {
            s1[j] += __shfl_xor(s1[j], 8);  s1[j] += __shfl_xor(s1[j], 16); s1[j] += __shfl_xor(s1[j], 32);
            s2[j] += __shfl_xor(s2[j], 8);  s2[j] += __shfl_xor(s2[j], 16); s2[j] += __shfl_xor(s2[j], 32);
            s3[j] += __shfl_xor(s3[j], 8);  s3[j] += __shfl_xor(s3[j], 16); s3[j] += __shfl_xor(s3[j], 32);
        }
        if (eslot == 0) {
            float4 icv = *(const float4*)(invc4 + (size_t)v * 4);
            f16* od = aggi + (size_t)v * 192 + cg * 8;
            f16x8 r1, r2, r3;
#pragma unroll
            for (int j = 0; j < 8; j++) {
                r1[j] = (f16)(s1[j] * icv.x);
                r2[j] = (f16)(s2[j] * icv.y);
                r3[j] = (f16)(s3[j] * icv.z);
            }
            *(f16x8*)(od)       = r1;
            *(f16x8*)(od + 64)  = r2;
            *(f16x8*)(od + 128) = r3;
        }
    }
}

// ---------- K6b: sage1 + fused proj (per branch) ----------
__global__ __launch_bounds__(256) void k_sage1(
    const f16* __restrict__ aggA, const f16* __restrict__ y1A,   // pre-offset by b*64, stride 192
    const float* __restrict__ WsageT, const float* __restrict__ bias21,
    const float* __restrict__ Wl3, const float* __restrict__ bl3,
    const float* __restrict__ Wr3,
    float* __restrict__ pz4, int b)
{
    __shared__ float wt[64 * 64];
    __shared__ float xt[128 * 68];
    __shared__ float wl[64], wr[64];
    int tid = threadIdx.x;
    int m0 = blockIdx.x * 128;
    int cg = tid & 15, rg = tid >> 4;
    if (tid < 64) { wl[tid] = Wl3[tid]; wr[tid] = Wr3[tid]; }
    float blv = bl3[0];
    float acc[8][4];
#pragma unroll
    for (int r = 0; r < 8; r++)
#pragma unroll
        for (int j = 0; j < 4; j++) acc[r][j] = 0.f;
    for (int ch = 0; ch < 2; ch++) {
        const f16* A = ch ? y1A : aggA;
        __syncthreads();
#pragma unroll
        for (int i = 0; i < 4; i++)
            ((float4*)wt)[i * 256 + tid] = ((const float4*)(WsageT + ch * 4096))[i * 256 + tid];
#pragma unroll
        for (int i = 0; i < 4; i++) {
            int li = i * 256 + tid;
            int rr = li >> 3, q = li & 7;
            int row = m0 + rr;
            f16x8 u = {};
            if (row < NN) u = *(const f16x8*)(A + (size_t)row * 192 + q * 8);
            float4 lo4 = make_float4((float)u[0], (float)u[1], (float)u[2], (float)u[3]);
            float4 hi4 = make_float4((float)u[4], (float)u[5], (float)u[6], (float)u[7]);
            *(float4*)(xt + rr * 68 + q * 8) = lo4;
            *(float4*)(xt + rr * 68 + q * 8 + 4) = hi4;
        }
        __syncthreads();
#pragma unroll 8
        for (int k = 0; k < 64; k++) {
            float4 wv = *(const float4*)(wt + k * 64 + cg * 4);
#pragma unroll
            for (int r = 0; r < 8; r++) {
                float xv = xt[(rg * 8 + r) * 68 + k];
                acc[r][0] += xv * wv.x; acc[r][1] += xv * wv.y;
                acc[r][2] += xv * wv.z; acc[r][3] += xv * wv.w;
            }
        }
    }
#pragma unroll
    for (int r = 0; r < 8; r++) {
        int row = m0 + rg * 8 + r;
        float ap = 0.f, az = 0.f;
#pragma unroll
        for (int j = 0; j < 4; j++) {
            float t = fmaxf(acc[r][j] + bias21[cg * 4 + j], 0.f);
            ap += t * wl[cg * 4 + j];
            az += t * wr[cg * 4 + j];
        }
        ap += __shfl_xor(ap, 1); ap += __shfl_xor(ap, 2);
        ap += __shfl_xor(ap, 4); ap += __shfl_xor(ap, 8);
        az += __shfl_xor(az, 1); az += __shfl_xor(az, 2);
        az += __shfl_xor(az, 4); az += __shfl_xor(az, 8);
        if (cg == 0 && row < NN) {
            pz4[(size_t)row * 4 + b] = ap;
            float zz = az + blv;
            if (b == 0) pz4[(size_t)row * 4 + 3] = zz;
            else        pz4[(size_t)row * 4 + 3] += zz;
        }
    }
}

// ---------- K8: fused 3-branch sage2 + sigmoid; persistent waves ----------
__global__ __launch_bounds__(256) void k_sage2_f(
    const int* __restrict__ rowptr, const int* __restrict__ sorted,
    const float* __restrict__ pz4, const float* __restrict__ invc4,
    float* __restrict__ outp)
{
    int wid = threadIdx.x >> 6, lane = threadIdx.x & 63;
    int gw = blockIdx.x * 4 + wid;
    for (int v = gw; v < NN; v += PWAVES) {
        int e0 = rowptr[v], e1 = rowptr[v + 1];
        float s1 = 0.f, s2 = 0.f, s3 = 0.f;
        for (int e = e0 + lane; e < e1; e += 64) {
            int w = sorted[e];
            int src = w & 0xFFFF, a = (w >> 16) & 3;
            float4 pz = *(const float4*)(pz4 + (size_t)src * 4);
            s3 += pz.z;
            if (a >= 1) s1 += pz.x;
            if (a <= 1) s2 += pz.y;
        }
#pragma unroll
        for (int off = 32; off > 0; off >>= 1) {
            s1 += __shfl_xor(s1, off);
            s2 += __shfl_xor(s2, off);
            s3 += __shfl_xor(s3, off);
        }
        if (lane == 0) {
            float4 icv = *(const float4*)(invc4 + (size_t)v * 4);
            float zsum = pz4[(size_t)v * 4 + 3];
            float val = s1 * icv.x + s2 * icv.y + s3 * icv.z + zsum;
            outp[v] = 1.f / (1.f + expf(-val));
        }
    }
}

// ---------- launch ----------
extern "C" void kernel_launch(void* const* d_in, const int* in_sizes, int n_in,
                              void* d_out, int out_size, void* d_ws, size_t ws_size,
                              hipStream_t stream)
{
    const float* x    = (const float*)d_in[0];
    const int* ei     = (const int*)d_in[1];
    const int* attr   = (const int*)d_in[2];
    const float* Wspf = (const float*)d_in[3];
    const float* bspf = (const float*)d_in[4];
    const float* W011 = (const float*)d_in[5];
    const float* b011 = (const float*)d_in[6];
    const float* W012 = (const float*)d_in[7];
    const float* b012 = (const float*)d_in[8];
    const float* bn01 = (const float*)d_in[9];
    const float* eW1[3] = { (const float*)d_in[10], (const float*)d_in[15], (const float*)d_in[20] };
    const float* eb1[3] = { (const float*)d_in[11], (const float*)d_in[16], (const float*)d_in[21] };
    const float* eW2[3] = { (const float*)d_in[12], (const float*)d_in[17], (const float*)d_in[22] };
    const float* eb2[3] = { (const float*)d_in[13], (const float*)d_in[18], (const float*)d_in[23] };
    const float* bn1[3] = { (const float*)d_in[14], (const float*)d_in[19], (const float*)d_in[24] };
    const float* s21Wl = (const float*)d_in[25];
    const float* s21bl = (const float*)d_in[26];
    const float* s21Wr = (const float*)d_in[27];
    const float* bn21  = (const float*)d_in[28];
    const float* s3Wl[3] = { (const float*)d_in[29], (const float*)d_in[32], (const float*)d_in[35] };
    const float* s3bl[3] = { (const float*)d_in[30], (const float*)d_in[33], (const float*)d_in[36] };
    const float* s3Wr[3] = { (const float*)d_in[31], (const float*)d_in[34], (const float*)d_in[37] };

    char* ws = (char*)d_ws;
    unsigned short* Whl = (unsigned short*)(ws + OFF_WHL);
    float* WspP   = (float*)(ws + OFF_WSPP);
    float* bias01 = (float*)(ws + OFF_BIAS01);
    float* W1pqT  = (float*)(ws + OFF_W1PQT);
    float* biasPQ = (float*)(ws + OFF_BIASPQ);
    float* WsageT = (float*)(ws + OFF_WSAGET);
    float* bias21 = (float*)(ws + OFF_BIAS21);
    float* bnf    = (float*)(ws + OFF_BNF);
    f16*   W2h    = (f16*)(ws + OFF_W2BF);
    float* invc4  = (float*)(ws + OFF_INVC4);
    float* pz4    = (float*)(ws + OFF_PZ4);
    int*   rp     = (int*)(ws + OFF_RP);
    int*   parts  = (int*)(ws + OFF_PARTS);
    int*   deg    = (int*)(ws + OFF_DEG);
    int*   ghead  = (int*)(ws + OFF_GHEAD);
    int*   sorted = (int*)(ws + OFF_SORT);
    unsigned int* ebuck = (unsigned int*)(ws + OFF_EBUCK);
    float* h      = (float*)(ws + OFF_H);
    f16*   Pi     = (f16*)(ws + OFF_PI);
    f16*   Qi     = (f16*)(ws + OFF_QI);
    f16*   y1i    = (f16*)(ws + OFF_Y1I);
    f16*   aggi   = (f16*)(ws + OFF_AGGI);   // overlays Pi (dead after edgeconv)

    hipMemsetAsync(ws + OFF_DEG, 0, 200064, stream);

    k_prep<<<689, 256, 0, stream>>>(
        Wspf, bspf, W011, b011, W012, b012, bn01,
        eW1[0], eb1[0], eb2[0], bn1[0],
        eW1[1], eb1[1], eb2[1], bn1[1],
        eW1[2], eb1[2], eb2[2], bn1[2],
        eW2[0], eW2[1], eW2[2],
        s21Wl, s21bl, s21Wr, bn21,
        Whl, WspP, bias01, W1pqT, biasPQ, WsageT, bias21, bnf, W2h);

    k_hist<<<3907, 256, 0, stream>>>(ei + EE, deg);
    k_psum<<<NBK, 256, 0, stream>>>(deg, parts);
    k_pscan<<<1, 256, 0, stream>>>(parts);
    k_scanfix<<<NBK, 256, 0, stream>>>(deg, parts, rp);
    k_gheadinit<<<1, 256, 0, stream>>>(rp, ghead);
    k_bucketA<<<245, 256, 0, stream>>>(ei, ei + EE, attr, ghead, ebuck);
    k_bucketB<<<NBK, 256, 0, stream>>>(rp, ebuck, sorted);

    k_h<<<3125, 256, 0, stream>>>(x, Whl, WspP, bias01, h);

    k_pq<<<782, 256, 0, stream>>>(h, W1pqT, biasPQ, Pi, Qi);

    k_edgeconv_f<<<PWAVES / 4, 256, 0, stream>>>(rp, sorted, Pi, Qi, W2h, bnf, y1i, invc4);
    k_agg_f<<<PWAVES / 4, 256, 0, stream>>>(rp, sorted, y1i, invc4, aggi);

    for (int b = 0; b < 3; b++)
        k_sage1<<<391, 256, 0, stream>>>(aggi + b * 64, y1i + b * 64, WsageT, bias21,
                                         s3Wl[b], s3bl[b], s3Wr[b], pz4, b);

    k_sage2_f<<<PWAVES / 4, 256, 0, stream>>>(rp, sorted, pz4, invc4, (float*)d_out);
}

// Round 7
// 757.907 us; speedup vs baseline: 1.1528x; 1.0163x over previous
//
#include <hip/hip_runtime.h>
#include <cstdint>
#include <cstddef>

#define NN 50000
#define EE 1000000
#define NBK 196          // dst buckets (dst>>8), 196*256 = 50176 >= NN
#define PW_EC 6144       // persistent waves, edgeconv (1536 blocks * 4; 6 blocks/CU LDS cap)
#define PW_AG 8192       // persistent waves, agg/sage2 (2048 blocks * 4)

typedef __attribute__((ext_vector_type(8))) short bf16x8;
typedef __attribute__((ext_vector_type(4))) short s16x4;
typedef __attribute__((ext_vector_type(4))) float f32x4;
typedef _Float16 f16;
typedef __attribute__((ext_vector_type(2))) _Float16 f16x2;
typedef __attribute__((ext_vector_type(4))) _Float16 f16x4;
typedef __attribute__((ext_vector_type(8))) _Float16 f16x8;

// truncation split: v == bf16(hi) + ~bf16(lo), residual ~2^-16 rel
__device__ __forceinline__ void split2(float v, short& hi, short& lo) {
    union { float f; unsigned int u; } a; a.f = v;
    unsigned short h16 = (unsigned short)(a.u >> 16);
    union { unsigned int u; float f; } hf; hf.u = ((unsigned int)h16) << 16;
    union { float f; unsigned int u; } b; b.f = v - hf.f;
    hi = (short)h16;
    lo = (short)(b.u >> 16);
}

// relu(p+q) in packed f16 (v_pk_add_f16 + v_pk_max_f16)
__device__ __forceinline__ f16x8 relupq(f16x8 p, f16x8 q) {
    f16x8 s = p + q;
    f16x8 z = {};
#if __has_builtin(__builtin_elementwise_max)
    return __builtin_elementwise_max(s, z);
#else
    f16x8 r;
#pragma unroll
    for (int j = 0; j < 8; j++) r[j] = (s[j] > (f16)0.f) ? s[j] : (f16)0.f;
    return r;
#endif
}

// ---------- workspace layout (byte offsets) ----------
#define OFF_WHL    ((size_t)0)          // 2*1024*64 bf16 = 262144
#define OFF_WSPP   ((size_t)262144)     // 64*4 f32
#define OFF_BIAS01 ((size_t)263168)     // 64 f32
#define OFF_W1PQT  ((size_t)263424)     // 3*64*128 f32
#define OFF_BIASPQ ((size_t)361728)     // 3*128 f32
#define OFF_WSAGET ((size_t)363264)     // 128*64 f32
#define OFF_BIAS21 ((size_t)396032)     // 64 f32
#define OFF_BNF    ((size_t)396288)     // 3*192 f32 (+pad to 2560)
#define OFF_W2BF   ((size_t)398848)     // 3*64*64 f16 = 24576
#define OFF_INVC4  ((size_t)423424)     // N*4 f32 = 800000 {ic1,ic2,ic3,0}
#define OFF_PZ4    ((size_t)1223424)    // N*4 f32 = 800000 {p1,p2,p3,zsum}
#define OFF_RP     ((size_t)2023424)    // (NN+1) i32 (+pad 200064)
#define OFF_PARTS  ((size_t)2223488)    // 256 i32 (+pad 4096)
#define OFF_DEG    ((size_t)2227584)    // N i32 (+pad 200064)
#define OFF_GHEAD  ((size_t)2427648)    // NBK i32 (+pad 4096)
#define OFF_SORT   ((size_t)2431744)    // E i32 = 4000000 (src | attr<<16)
#define OFF_H      ((size_t)6431744)    // N*64 f32 = 12800000
#define OFF_PI     ((size_t)19231744)   // N*192 f16 = 19200000 (P, interleaved 3 branches)
#define OFF_QI     ((size_t)38431744)   // N*192 f16 = 19200000 (Q, interleaved)
#define OFF_Y1I    ((size_t)57631744)   // N*192 f16 = 19200000 (end 76831744)
#define OFF_EBUCK  OFF_H                // overlay: E u32, dead before k_h
#define OFF_AGGI   OFF_PI               // overlay: N*192 f16, Pi dead after edgeconv

// ---------- K1: weight prep / folding ----------
__global__ __launch_bounds__(256) void k_prep(
    const float* __restrict__ Wspf, const float* __restrict__ bspf,
    const float* __restrict__ W011, const float* __restrict__ b011,
    const float* __restrict__ W012, const float* __restrict__ b012,
    const float* __restrict__ bn01,
    const float* __restrict__ e1W1, const float* __restrict__ e1b1,
    const float* __restrict__ e1b2, const float* __restrict__ bn11,
    const float* __restrict__ e2W1, const float* __restrict__ e2b1,
    const float* __restrict__ e2b2, const float* __restrict__ bn12,
    const float* __restrict__ e3W1, const float* __restrict__ e3b1,
    const float* __restrict__ e3b2, const float* __restrict__ bn13,
    const float* __restrict__ e1W2, const float* __restrict__ e2W2,
    const float* __restrict__ e3W2,
    const float* __restrict__ s21Wl, const float* __restrict__ s21bl,
    const float* __restrict__ s21Wr, const float* __restrict__ bn21,
    unsigned short* __restrict__ Whl, float* __restrict__ WspP, float* __restrict__ bias01,
    float* __restrict__ W1pqT, float* __restrict__ biasPQ,
    float* __restrict__ WsageT, float* __restrict__ bias21, float* __restrict__ bnf,
    f16* __restrict__ W2h)
{
    int idx = blockIdx.x * 256 + threadIdx.x;
    if (idx < 131072) {
        int hl = idx >> 16;
        int r = idx & 65535;
        int kchunk = r >> 11;
        int r2 = r & 2047;
        int blk = r2 >> 9;
        int r3 = r2 & 511;
        int lane = r3 >> 3;
        int j = r3 & 7;
        int n = lane & 15, quad = lane >> 4;
        int k = kchunk * 32 + quad * 8 + j;
        int c = blk * 16 + n;
        float s = bn01[c] * rsqrtf(bn01[192 + c] + 1e-5f);
        float w = ((k < 512) ? W012[c * 512 + k] : W011[c * 576 + (k - 512)]) * s;
        short hi, lo;
        split2(w, hi, lo);
        Whl[idx] = (unsigned short)(hl ? lo : hi);
    } else if (idx < 131072 + 24576) {
        int r = idx - 131072;
        int b = r >> 13; r &= 8191;
        int k = r >> 7, cp = r & 127;
        const float* W1 = (b == 0) ? e1W1 : (b == 1) ? e2W1 : e3W1;
        float val;
        if (cp < 64) val = W1[cp * 128 + k] - W1[cp * 128 + 64 + k];
        else         val = W1[(cp - 64) * 128 + 64 + k];
        W1pqT[b * 8192 + k * 128 + cp] = val;
    } else if (idx < 131072 + 24576 + 8192) {
        int r = idx - (131072 + 24576);
        int k = r >> 6, c = r & 63;
        float s = bn21[c] * rsqrtf(bn21[192 + c] + 1e-5f);
        float w = (k < 64) ? s21Wl[c * 64 + k] : s21Wr[c * 64 + (k - 64)];
        WsageT[k * 64 + c] = w * s;
    } else if (idx < 131072 + 24576 + 8192 + 64) {
        int c = idx - (131072 + 24576 + 8192);
        float s01 = bn01[c] * rsqrtf(bn01[192 + c] + 1e-5f);
        float wsp0 = 0.f, wsp1 = 0.f, wsp2 = 0.f, wsp3 = 0.f, bacc = 0.f;
        for (int j = 0; j < 64; j++) {
            float w = W011[c * 576 + 512 + j];
            wsp0 += w * Wspf[j * 4 + 0];
            wsp1 += w * Wspf[j * 4 + 1];
            wsp2 += w * Wspf[j * 4 + 2];
            wsp3 += w * Wspf[j * 4 + 3];
            bacc += w * bspf[j];
        }
        WspP[c * 4 + 0] = wsp0 * s01; WspP[c * 4 + 1] = wsp1 * s01;
        WspP[c * 4 + 2] = wsp2 * s01; WspP[c * 4 + 3] = wsp3 * s01;
        bias01[c] = (b011[c] + b012[c] + bacc) * s01 + (bn01[64 + c] - bn01[128 + c] * s01);
        float s21 = bn21[c] * rsqrtf(bn21[192 + c] + 1e-5f);
        bias21[c] = s21bl[c] * s21 + (bn21[64 + c] - bn21[128 + c] * s21);
        const float* b1a[3] = { e1b1, e2b1, e3b1 };
        const float* b2a[3] = { e1b2, e2b2, e3b2 };
        const float* bna[3] = { bn11, bn12, bn13 };
#pragma unroll
        for (int b = 0; b < 3; b++) {
            float s = bna[b][c] * rsqrtf(bna[b][192 + c] + 1e-5f);
            float tr = bna[b][64 + c] - bna[b][128 + c] * s;
            bnf[b * 192 + c] = s;
            bnf[b * 192 + 64 + c] = b2a[b][c] * s + tr;
            bnf[b * 192 + 128 + c] = tr;
            biasPQ[b * 128 + c] = b1a[b][c];
            biasPQ[b * 128 + 64 + c] = 0.f;
        }
    } else if (idx < 131072 + 24576 + 8192 + 64 + 12288) {
        int r = idx - (131072 + 24576 + 8192 + 64);
        int b = r >> 12, i = r & 4095;
        const float* W2 = (b == 0) ? e1W2 : (b == 1) ? e2W2 : e3W2;
        W2h[b * 4096 + i] = (f16)W2[i];
    }
}

// ---------- degree histogram (single, all edges) ----------
__global__ __launch_bounds__(256) void k_hist(
    const int* __restrict__ dst, int* __restrict__ deg)
{
    int e = blockIdx.x * 256 + threadIdx.x;
    if (e < EE) atomicAdd(&deg[dst[e]], 1);
}

__global__ __launch_bounds__(256) void k_psum(const int* __restrict__ deg, int* __restrict__ parts)
{
    int i = blockIdx.x * 256 + threadIdx.x;
    int v = (i < NN) ? deg[i] : 0;
#pragma unroll
    for (int off = 32; off > 0; off >>= 1) v += __shfl_xor(v, off);
    __shared__ int ws4[4];
    int wid = threadIdx.x >> 6;
    if ((threadIdx.x & 63) == 0) ws4[wid] = v;
    __syncthreads();
    if (threadIdx.x == 0)
        parts[blockIdx.x] = ws4[0] + ws4[1] + ws4[2] + ws4[3];
}

// exclusive scan of bucket counts; also emits ghead (= bucket base = rp[b*256])
__global__ __launch_bounds__(256) void k_pscan(int* __restrict__ parts, int* __restrict__ ghead)
{
    __shared__ int sbuf[256];
    int tid = threadIdx.x;
    int v = (tid < NBK) ? parts[tid] : 0;
    sbuf[tid] = v;
    __syncthreads();
    for (int off = 1; off < 256; off <<= 1) {
        int t = (tid >= off) ? sbuf[tid - off] : 0;
        __syncthreads();
        sbuf[tid] += t;
        __syncthreads();
    }
    if (tid < NBK) {
        int ex = sbuf[tid] - v;
        parts[tid] = ex;
        ghead[tid] = ex;
    }
}

__global__ __launch_bounds__(256) void k_scanfix(
    const int* __restrict__ deg, const int* __restrict__ parts, int* __restrict__ rowptr)
{
    __shared__ int sbuf[256];
    int tid = threadIdx.x;
    int i = blockIdx.x * 256 + tid;
    int v = (i < NN) ? deg[i] : 0;
    sbuf[tid] = v;
    __syncthreads();
    for (int off = 1; off < 256; off <<= 1) {
        int t = (tid >= off) ? sbuf[tid - off] : 0;
        __syncthreads();
        sbuf[tid] += t;
        __syncthreads();
    }
    int base = parts[blockIdx.x];
    if (i < NN)      rowptr[i] = base + sbuf[tid] - v;
    if (i == NN - 1) rowptr[NN] = base + sbuf[tid];
}

// ---------- bucketed sort pass A: partition edges into dst-buckets ----------
__global__ __launch_bounds__(256) void k_bucketA(
    const int* __restrict__ src, const int* __restrict__ dst, const int* __restrict__ attr,
    int* __restrict__ ghead, unsigned int* __restrict__ ebuck)
{
    __shared__ int hist[NBK];
    __shared__ int head[NBK];
    int tid = threadIdx.x;
    if (tid < NBK) hist[tid] = 0;
    __syncthreads();
    int base_e = blockIdx.x * 4096;
    unsigned int word[16]; int bkt[16];
#pragma unroll
    for (int k = 0; k < 16; k++) {
        int e = base_e + k * 256 + tid;
        if (e < EE) {
            int d = dst[e], s = src[e], a = attr[e] + 1;
            int b = d >> 8;
            word[k] = (unsigned)s | ((unsigned)a << 16) | ((unsigned)(d & 255) << 18);
            bkt[k] = b;
            atomicAdd(&hist[b], 1);
        } else { bkt[k] = -1; word[k] = 0; }
    }
    __syncthreads();
    if (tid < NBK) {
        int c = hist[tid];
        head[tid] = c ? atomicAdd(&ghead[tid], c) : 0;
    }
    __syncthreads();
#pragma unroll
    for (int k = 0; k < 16; k++) {
        if (bkt[k] >= 0) {
            int pos = atomicAdd(&head[bkt[k]], 1);
            ebuck[pos] = word[k];
        }
    }
}

// ---------- bucketed sort pass B: exact dst sort within bucket ----------
__global__ __launch_bounds__(256) void k_bucketB(
    const int* __restrict__ rp, const unsigned int* __restrict__ ebuck,
    int* __restrict__ sorted)
{
    __shared__ int sbuf[256];
    __shared__ int head[256];
    int b = blockIdx.x, tid = threadIdx.x;
    int n0 = b * 256;
    int n1 = n0 + 256; if (n1 > NN) n1 = NN;
    int r0 = rp[n0];
    int r1 = rp[n1];
    sbuf[tid] = 0;
    __syncthreads();
    for (int e = r0 + tid; e < r1; e += 256)
        atomicAdd(&sbuf[(ebuck[e] >> 18) & 255], 1);
    __syncthreads();
    int v = sbuf[tid];
    for (int off = 1; off < 256; off <<= 1) {
        int t = (tid >= off) ? sbuf[tid - off] : 0;
        __syncthreads();
        sbuf[tid] += t;
        __syncthreads();
    }
    head[tid] = r0 + sbuf[tid] - v;
    __syncthreads();
    for (int e = r0 + tid; e < r1; e += 256) {
        unsigned int w = ebuck[e];
        int pos = atomicAdd(&head[(w >> 18) & 255], 1);
        sorted[pos] = (int)(w & 0x3FFFFu);   // src | attr<<16
    }
}

// ---------- K2: h = relu(fold_bn01(x @ Wc')) ----------
__global__ __launch_bounds__(256) void k_h(
    const float* __restrict__ x, const unsigned short* __restrict__ Whl,
    const float* __restrict__ WspP, const float* __restrict__ bias01,
    float* __restrict__ h)
{
    __shared__ unsigned short hib[2][4096];
    __shared__ unsigned short lob[2][4096];
    int tid = threadIdx.x;
    int w = tid >> 6, l = tid & 63;
    int tile = blockIdx.x;
    int m = l & 15, quad = l >> 4;
    int blk = w;
    const unsigned short* Wh = Whl;
    const unsigned short* Wl = Whl + 65536;
    const size_t xbase = (size_t)tile * 16 * 1028;

    int oct_w = l >> 1, off_w = (l & 1) * 4;

    f32x4 g[4];
#pragma unroll
    for (int p = 0; p < 4; p++)
        g[p] = *(const f32x4*)(x + xbase + (size_t)(p * 4 + w) * 1028 + l * 4);
#pragma unroll
    for (int p = 0; p < 4; p++) {
        int r = p * 4 + w;
        int op = r * 256 + (oct_w ^ (r & 7)) * 8 + off_w;
        s16x4 h4, l4;
#pragma unroll
        for (int i = 0; i < 4; i++) { short hi, lo; split2(g[p][i], hi, lo); h4[i] = hi; l4[i] = lo; }
        *(s16x4*)(&hib[0][op]) = h4;
        *(s16x4*)(&lob[0][op]) = l4;
    }
    __syncthreads();

    f32x4 acc = { 0.f, 0.f, 0.f, 0.f };
    for (int c = 0; c < 4; c++) {
        if (c < 3) {
#pragma unroll
            for (int p = 0; p < 4; p++)
                g[p] = *(const f32x4*)(x + xbase + (size_t)(p * 4 + w) * 1028 + (c + 1) * 256 + l * 4);
        }
        int buf = c & 1;
        const unsigned short* hp = &hib[buf][m * 256];
        const unsigned short* lp = &lob[buf][m * 256];
        int msw = m & 7;
#pragma unroll
        for (int ks = 0; ks < 8; ks++) {
            int oct = ks * 4 + quad;
            int ao = (oct ^ msw) * 8;
            bf16x8 xh = *(const bf16x8*)(hp + ao);
            bf16x8 xl = *(const bf16x8*)(lp + ao);
            int fb = (c * 8 + ks) * 2048 + blk * 512 + l * 8;
            bf16x8 bh = *(const bf16x8*)(Wh + fb);
            bf16x8 bl = *(const bf16x8*)(Wl + fb);
            acc = __builtin_amdgcn_mfma_f32_16x16x32_bf16(xh, bh, acc, 0, 0, 0);
            acc = __builtin_amdgcn_mfma_f32_16x16x32_bf16(xl, bh, acc, 0, 0, 0);
            acc = __builtin_amdgcn_mfma_f32_16x16x32_bf16(xh, bl, acc, 0, 0, 0);
        }
        if (c < 3) {
            int nbuf = (c + 1) & 1;
#pragma unroll
            for (int p = 0; p < 4; p++) {
                int r = p * 4 + w;
                int op = r * 256 + (oct_w ^ (r & 7)) * 8 + off_w;
                s16x4 h4, l4;
#pragma unroll
                for (int i = 0; i < 4; i++) { short hi, lo; split2(g[p][i], hi, lo); h4[i] = hi; l4[i] = lo; }
                *(s16x4*)(&hib[nbuf][op]) = h4;
                *(s16x4*)(&lob[nbuf][op]) = l4;
            }
            __syncthreads();
        }
    }

    int ch = blk * 16 + m;
    f32x4 wsp = *(const f32x4*)(WspP + ch * 4);
    float bia = bias01[ch];
#pragma unroll
    for (int r = 0; r < 4; r++) {
        int row = tile * 16 + quad * 4 + r;
        f32x4 sp = *(const f32x4*)(x + (size_t)row * 1028 + 1024);
        float a = acc[r] + sp[0] * wsp[0] + sp[1] * wsp[1]
                + sp[2] * wsp[2] + sp[3] * wsp[3] + bia;
        h[(size_t)row * 64 + ch] = fmaxf(a, 0.f);
    }
}

// ---------- K4: all 3 branches fused: P = h @ W1p' + b1 (f16), Q = h @ W1q' (f16) ----------
__global__ __launch_bounds__(256) void k_pq(
    const float* __restrict__ h, const float* __restrict__ WT3,
    const float* __restrict__ biasPQ, f16* __restrict__ Pi, f16* __restrict__ Qi)
{
    __shared__ float wt[64 * 128];
    __shared__ float xt[64 * 68];
    int tid = threadIdx.x;
    int m0 = blockIdx.x * 64;
    int cg = tid & 31, rg = tid >> 5;
#pragma unroll
    for (int i = 0; i < 4; i++) {
        int li = i * 256 + tid;
        int rr = li >> 4, q = li & 15;
        int row = m0 + rr;
        float4 u = make_float4(0.f, 0.f, 0.f, 0.f);
        if (row < NN) u = *(const float4*)(h + (size_t)row * 64 + q * 4);
        *(float4*)(xt + rr * 68 + q * 4) = u;
    }
    for (int b = 0; b < 3; b++) {
        __syncthreads();
#pragma unroll
        for (int i = 0; i < 8; i++)
            ((float4*)wt)[i * 256 + tid] = ((const float4*)(WT3 + b * 8192))[i * 256 + tid];
        __syncthreads();
        float acc[8][4];
#pragma unroll
        for (int r = 0; r < 8; r++)
#pragma unroll
            for (int j = 0; j < 4; j++) acc[r][j] = 0.f;
#pragma unroll 8
        for (int k = 0; k < 64; k++) {
            float4 wv = *(const float4*)(wt + k * 128 + cg * 4);
#pragma unroll
            for (int r = 0; r < 8; r++) {
                float xv = xt[(rg * 8 + r) * 68 + k];
                acc[r][0] += xv * wv.x; acc[r][1] += xv * wv.y;
                acc[r][2] += xv * wv.z; acc[r][3] += xv * wv.w;
            }
        }
        const float* biasP = biasPQ + b * 128;
#pragma unroll
        for (int r = 0; r < 8; r++) {
            int row = m0 + rg * 8 + r;
            if (row < NN) {
                if (cg < 16) {               // P half (+bias), fp16
                    f16x4 res;
#pragma unroll
                    for (int j = 0; j < 4; j++)
                        res[j] = (f16)(acc[r][j] + biasP[cg * 4 + j]);
                    *(f16x4*)(Pi + (size_t)row * 192 + b * 64 + cg * 4) = res;
                } else {                     // Q half, fp16
                    f16x4 res;
#pragma unroll
                    for (int j = 0; j < 4; j++)
                        res[j] = (f16)acc[r][j];
                    *(f16x4*)(Qi + (size_t)row * 192 + b * 64 + (cg - 16) * 4) = res;
                }
            }
        }
    }
}

// per-branch batch body: packed-f16 A-fragment, f16 MFMA, W2 frags from LDS
#define ECV_LDS_BRANCH(B, PL, PH, Q0, Q1, MASK, ACC)                               \
    if ((MASK) & 0xFFFFull) {                                                      \
        f16x8 a0 = relupq(PL, Q0);                                                 \
        f16x8 a1 = relupq(PH, Q1);                                                 \
        _Pragma("unroll") for (int blk = 0; blk < 4; blk++) {                      \
            f32x4 c = { 0.f, 0.f, 0.f, 0.f };                                      \
            f16x8 w0 = *(const f16x8*)(w2s + ((B) * 8 + blk * 2 + 0) * 512 + quad * 128 + m * 8); \
            f16x8 w1 = *(const f16x8*)(w2s + ((B) * 8 + blk * 2 + 1) * 512 + quad * 128 + m * 8); \
            c = __builtin_amdgcn_mfma_f32_16x16x32_f16(a0, w0, c, 0, 0, 0);        \
            c = __builtin_amdgcn_mfma_f32_16x16x32_f16(a1, w1, c, 0, 0, 0);        \
            _Pragma("unroll") for (int r = 0; r < 4; r++)                          \
                if (((MASK) >> (vsh + r)) & 1)                                     \
                    ACC[blk][r] = fmaxf(ACC[blk][r], c[r]);                        \
        }                                                                          \
    }

#define ECV_EPI(B, ACC, CNT)                                                       \
    {                                                                              \
        float red[4];                                                              \
        _Pragma("unroll") for (int blk = 0; blk < 4; blk++) {                      \
            float rv = fmaxf(fmaxf(ACC[blk][0], ACC[blk][1]),                      \
                             fmaxf(ACC[blk][2], ACC[blk][3]));                     \
            rv = fmaxf(rv, __shfl_xor(rv, 16));                                    \
            rv = fmaxf(rv, __shfl_xor(rv, 32));                                    \
            red[blk] = rv;                                                         \
        }                                                                          \
        float mx = red[quad];                                                      \
        const float* scb = bnf + (B) * 192;                                        \
        float outv = ((CNT) > 0) ? fmaxf(fmaf(mx, scb[lane], scb[64 + lane]), 0.f) \
                                 : fmaxf(scb[128 + lane], 0.f);                    \
        y1i[(size_t)v * 192 + (B) * 64 + lane] = (f16)outv;                        \
    }

// ---------- K5: fused 3-branch EdgeConv; persistent waves; all W2 in LDS ----------
// branch 3 (all edges) accumulates unmasked on full batches; mask only on the tail batch.
__global__ __launch_bounds__(256) void k_edgeconv_f(
    const int* __restrict__ rowptr, const int* __restrict__ sorted,
    const f16* __restrict__ Pi, const f16* __restrict__ Qi,
    const f16* __restrict__ W2h,               // 3*64*64 f16
    const float* __restrict__ bnf,             // 3*192
    f16* __restrict__ y1i, float* __restrict__ invc4)
{
    __shared__ f16 w2s[12288];                 // 3 branches : 24 frags * 512 halves, bank-permuted
    int tid = threadIdx.x;
#pragma unroll
    for (int u0 = 0; u0 < 6; u0++) {
        int u = u0 * 256 + tid;                // 0..1535
        int frag = u >> 6;                     // b*8 + blk*2 + kc   (b in {0,1,2})
        int rem = u & 63;
        int m2 = rem >> 2, qd = rem & 3;
        int bb = frag >> 3, blk = (frag >> 1) & 3, kc = frag & 1;
        *(int4*)(w2s + frag * 512 + qd * 128 + m2 * 8) =
            *(const int4*)(W2h + (bb * 64 + blk * 16 + m2) * 64 + kc * 32 + qd * 8);
    }
    __syncthreads();

    int wid = tid >> 6, lane = tid & 63;
    int m = lane & 15, quad = lane >> 4;
    int gw = blockIdx.x * 4 + wid;             // persistent wave id, PW_EC total

    for (int v = gw; v < NN; v += PW_EC) {
        const f16* pr = Pi + (size_t)v * 192;
        f16x8 pl0 = *(const f16x8*)(pr + 0   + quad * 8);
        f16x8 ph0 = *(const f16x8*)(pr + 32  + quad * 8);
        f16x8 pl1 = *(const f16x8*)(pr + 64  + quad * 8);
        f16x8 ph1 = *(const f16x8*)(pr + 96  + quad * 8);
        f16x8 pl2 = *(const f16x8*)(pr + 128 + quad * 8);
        f16x8 ph2 = *(const f16x8*)(pr + 160 + quad * 8);

        int e0 = rowptr[v], e1 = rowptr[v + 1];
        int deg = e1 - e0;
        float acc0[4][4], acc1[4][4], acc2[4][4];
#pragma unroll
        for (int blk = 0; blk < 4; blk++)
#pragma unroll
            for (int r = 0; r < 4; r++) {
                acc0[blk][r] = -3.0e38f; acc1[blk][r] = -3.0e38f; acc2[blk][r] = -3.0e38f;
            }

        int cnt1 = 0, cnt2 = 0;
        int vsh = quad * 4;
        int nb = (deg + 15) >> 4;
        bool hastail = (deg & 15) != 0;
        for (int bi = 0; bi < nb; bi++) {
            bool tailb = hastail && (bi == nb - 1);   // wave-uniform
            int e = e0 + bi * 16 + m;
            bool inn = tailb ? (e < e1) : true;
            int wrd = inn ? sorted[e] : 0;
            int srcm = inn ? (wrd & 0xFFFF) : v;
            int a = (wrd >> 16) & 3;
            bool mm1 = inn && (a >= 1);
            bool mm2 = inn && (a <= 1);
            const f16* qr = Qi + (size_t)srcm * 192;
            f16x8 q30 = *(const f16x8*)(qr + 128 + quad * 8);
            f16x8 q31 = *(const f16x8*)(qr + 160 + quad * 8);
            f16x8 q10 = {}, q11 = {}, q20 = {}, q21 = {};
            if (mm1) { q10 = *(const f16x8*)(qr + quad * 8);      q11 = *(const f16x8*)(qr + 32 + quad * 8); }
            if (mm2) { q20 = *(const f16x8*)(qr + 64 + quad * 8); q21 = *(const f16x8*)(qr + 96 + quad * 8); }
            unsigned long long bl1 = __ballot(mm1);
            unsigned long long bl2 = __ballot(mm2);
            cnt1 += __popc((unsigned)bl1 & 0xFFFFu);
            cnt2 += __popc((unsigned)bl2 & 0xFFFFu);

            // branch 3
            {
                f16x8 a30 = relupq(pl2, q30);
                f16x8 a31 = relupq(ph2, q31);
                if (!tailb) {                  // full batch: no row mask needed
#pragma unroll
                    for (int blk = 0; blk < 4; blk++) {
                        f32x4 c = { 0.f, 0.f, 0.f, 0.f };
                        f16x8 w0 = *(const f16x8*)(w2s + (16 + blk * 2 + 0) * 512 + quad * 128 + m * 8);
                        f16x8 w1 = *(const f16x8*)(w2s + (16 + blk * 2 + 1) * 512 + quad * 128 + m * 8);
                        c = __builtin_amdgcn_mfma_f32_16x16x32_f16(a30, w0, c, 0, 0, 0);
                        c = __builtin_amdgcn_mfma_f32_16x16x32_f16(a31, w1, c, 0, 0, 0);
#pragma unroll
                        for (int r = 0; r < 4; r++)
                            acc2[blk][r] = fmaxf(acc2[blk][r], c[r]);
                    }
                } else {
                    unsigned long long bl3 = __ballot(inn);
#pragma unroll
                    for (int blk = 0; blk < 4; blk++) {
                        f32x4 c = { 0.f, 0.f, 0.f, 0.f };
                        f16x8 w0 = *(const f16x8*)(w2s + (16 + blk * 2 + 0) * 512 + quad * 128 + m * 8);
                        f16x8 w1 = *(const f16x8*)(w2s + (16 + blk * 2 + 1) * 512 + quad * 128 + m * 8);
                        c = __builtin_amdgcn_mfma_f32_16x16x32_f16(a30, w0, c, 0, 0, 0);
                        c = __builtin_amdgcn_mfma_f32_16x16x32_f16(a31, w1, c, 0, 0, 0);
#pragma unroll
                        for (int r = 0; r < 4; r++)
                            if ((bl3 >> (vsh + r)) & 1)
                                acc2[blk][r] = fmaxf(acc2[blk][r], c[r]);
                    }
                }
            }
            ECV_LDS_BRANCH(0, pl0, ph0, q10, q11, bl1, acc0)
            ECV_LDS_BRANCH(1, pl1, ph1, q20, q21, bl2, acc1)
        }

        ECV_EPI(0, acc0, cnt1)
        ECV_EPI(1, acc1, cnt2)
        ECV_EPI(2, acc2, deg)
        if (lane == 0) {
            float4 ic;
            ic.x = 1.f / (float)(cnt1 > 0 ? cnt1 : 1);
            ic.y = 1.f / (float)(cnt2 > 0 ? cnt2 : 1);
            ic.z = 1.f / (float)(deg  > 0 ? deg  : 1);
            ic.w = 0.f;
            *(float4*)(invc4 + (size_t)v * 4) = ic;
        }
    }
}

// ---------- K6a: fused 3-branch mean aggregation; 8 lanes/edge, conditional slice loads ----------
__global__ __launch_bounds__(256) void k_agg_f(
    const int* __restrict__ rowptr, const int* __restrict__ sorted,
    const f16* __restrict__ y1i, const float* __restrict__ invc4,
    f16* __restrict__ aggi)
{
    int wid = threadIdx.x >> 6, lane = threadIdx.x & 63;
    int eslot = lane >> 3, cg = lane & 7;
    int gw = blockIdx.x * 4 + wid;
    for (int v = gw; v < NN; v += PW_AG) {
        int e0 = rowptr[v], e1 = rowptr[v + 1];
        float s1[8], s2[8], s3[8];
#pragma unroll
        for (int j = 0; j < 8; j++) { s1[j] = 0.f; s2[j] = 0.f; s3[j] = 0.f; }
        for (int eb = e0; eb < e1; eb += 8) {
            int e = eb + eslot;
            if (e < e1) {                     // diverges at 8-lane granularity (tail only)
                int w = sorted[e];
                int src = w & 0xFFFF, a = (w >> 16) & 3;
                const f16* row = y1i + (size_t)src * 192 + cg * 8;
                f16x8 u3 = *(const f16x8*)(row + 128);
#pragma unroll
                for (int j = 0; j < 8; j++) s3[j] += (float)u3[j];
                if (a >= 1) {                 // a uniform within the 8-lane group
                    f16x8 u1 = *(const f16x8*)(row);
#pragma unroll
                    for (int j = 0; j < 8; j++) s1[j] += (float)u1[j];
                }
                if (a <= 1) {
                    f16x8 u2 = *(const f16x8*)(row + 64);
#pragma unroll
                    for (int j = 0; j < 8; j++) s2[j] += (float)u2[j];
                }
            }
        }
        // reduce across the 8 edge-slots (lane bits 3,4,5)
#pragma unroll
        for (int j = 0; j < 8; j++) {
            s1[j] += __shfl_xor(s1[j], 8);  s1[j] += __shfl_xor(s1[j], 16); s1[j] += __shfl_xor(s1[j], 32);
            s2[j] += __shfl_xor(s2[j], 8);  s2[j] += __shfl_xor(s2[j], 16); s2[j] += __shfl_xor(s2[j], 32);
            s3[j] += __shfl_xor(s3[j], 8);  s3[j] += __shfl_xor(s3[j], 16); s3[j] += __shfl_xor(s3[j], 32);
        }
        if (eslot == 0) {
            float4 icv = *(const float4*)(invc4 + (size_t)v * 4);
            f16* od = aggi + (size_t)v * 192 + cg * 8;
            f16x8 r1, r2, r3;
#pragma unroll
            for (int j = 0; j < 8; j++) {
                r1[j] = (f16)(s1[j] * icv.x);
                r2[j] = (f16)(s2[j] * icv.y);
                r3[j] = (f16)(s3[j] * icv.z);
            }
            *(f16x8*)(od)       = r1;
            *(f16x8*)(od + 64)  = r2;
            *(f16x8*)(od + 128) = r3;
        }
    }
}

// ---------- K6b: sage1 + fused proj, all 3 branches in one kernel ----------
__global__ __launch_bounds__(256) void k_sage1(
    const f16* __restrict__ aggi, const f16* __restrict__ y1i,
    const float* __restrict__ WsageT, const float* __restrict__ bias21,
    const float* __restrict__ Wl0, const float* __restrict__ bl0, const float* __restrict__ Wr0,
    const float* __restrict__ Wl1, const float* __restrict__ bl1, const float* __restrict__ Wr1,
    const float* __restrict__ Wl2, const float* __restrict__ bl2, const float* __restrict__ Wr2,
    float* __restrict__ pz4)
{
    __shared__ float wt[64 * 64];
    __shared__ float xt[128 * 68];
    __shared__ float wl[64], wr[64];
    int tid = threadIdx.x;
    int m0 = blockIdx.x * 128;
    int cg = tid & 15, rg = tid >> 4;
    float zsum[8];
#pragma unroll
    for (int r = 0; r < 8; r++) zsum[r] = 0.f;

    for (int b = 0; b < 3; b++) {
        const float* Wl3 = (b == 0) ? Wl0 : (b == 1) ? Wl1 : Wl2;
        const float* bl3 = (b == 0) ? bl0 : (b == 1) ? bl1 : bl2;
        const float* Wr3 = (b == 0) ? Wr0 : (b == 1) ? Wr1 : Wr2;
        __syncthreads();                     // guard wl/wr overwrite vs prior epilogue reads
        if (tid < 64) { wl[tid] = Wl3[tid]; wr[tid] = Wr3[tid]; }
        float blv = bl3[0];
        float acc[8][4];
#pragma unroll
        for (int r = 0; r < 8; r++)
#pragma unroll
            for (int j = 0; j < 4; j++) acc[r][j] = 0.f;
        for (int ch = 0; ch < 2; ch++) {
            const f16* A = (ch ? y1i : aggi) + b * 64;
            __syncthreads();
#pragma unroll
            for (int i = 0; i < 4; i++)
                ((float4*)wt)[i * 256 + tid] = ((const float4*)(WsageT + ch * 4096))[i * 256 + tid];
#pragma unroll
            for (int i = 0; i < 4; i++) {
                int li = i * 256 + tid;
                int rr = li >> 3, q = li & 7;
                int row = m0 + rr;
                f16x8 u = {};
                if (row < NN) u = *(const f16x8*)(A + (size_t)row * 192 + q * 8);
                float4 lo4 = make_float4((float)u[0], (float)u[1], (float)u[2], (float)u[3]);
                float4 hi4 = make_float4((float)u[4], (float)u[5], (float)u[6], (float)u[7]);
                *(float4*)(xt + rr * 68 + q * 8) = lo4;
                *(float4*)(xt + rr * 68 + q * 8 + 4) = hi4;
            }
            __syncthreads();
#pragma unroll 8
            for (int k = 0; k < 64; k++) {
                float4 wv = *(const float4*)(wt + k * 64 + cg * 4);
#pragma unroll
                for (int r = 0; r < 8; r++) {
                    float xv = xt[(rg * 8 + r) * 68 + k];
                    acc[r][0] += xv * wv.x; acc[r][1] += xv * wv.y;
                    acc[r][2] += xv * wv.z; acc[r][3] += xv * wv.w;
                }
            }
        }
#pragma unroll
        for (int r = 0; r < 8; r++) {
            int row = m0 + rg * 8 + r;
            float ap = 0.f, az = 0.f;
#pragma unroll
            for (int j = 0; j < 4; j++) {
                float t = fmaxf(acc[r][j] + bias21[cg * 4 + j], 0.f);
                ap += t * wl[cg * 4 + j];
                az += t * wr[cg * 4 + j];
            }
            ap += __shfl_xor(ap, 1); ap += __shfl_xor(ap, 2);
            ap += __shfl_xor(ap, 4); ap += __shfl_xor(ap, 8);
            az += __shfl_xor(az, 1); az += __shfl_xor(az, 2);
            az += __shfl_xor(az, 4); az += __shfl_xor(az, 8);
            zsum[r] += az + blv;
            if (cg == 0 && row < NN)
                pz4[(size_t)row * 4 + b] = ap;
        }
    }
#pragma unroll
    for (int r = 0; r < 8; r++) {
        int row = m0 + rg * 8 + r;
        if (cg == 0 && row < NN)
            pz4[(size_t)row * 4 + 3] = zsum[r];
    }
}

// ---------- K8: fused 3-branch sage2 + sigmoid; persistent waves ----------
__global__ __launch_bounds__(256) void k_sage2_f(
    const int* __restrict__ rowptr, const int* __restrict__ sorted,
    const float* __restrict__ pz4, const float* __restrict__ invc4,
    float* __restrict__ outp)
{
    int wid = threadIdx.x >> 6, lane = threadIdx.x & 63;
    int gw = blockIdx.x * 4 + wid;
    for (int v = gw; v < NN; v += PW_AG) {
        int e0 = rowptr[v], e1 = rowptr[v + 1];
        float s1 = 0.f, s2 = 0.f, s3 = 0.f;
        for (int e = e0 + lane; e < e1; e += 64) {
            int w = sorted[e];
            int src = w & 0xFFFF, a = (w >> 16) & 3;
            float4 pz = *(const float4*)(pz4 + (size_t)src * 4);
            s3 += pz.z;
            if (a >= 1) s1 += pz.x;
            if (a <= 1) s2 += pz.y;
        }
#pragma unroll
        for (int off = 32; off > 0; off >>= 1) {
            s1 += __shfl_xor(s1, off);
            s2 += __shfl_xor(s2, off);
            s3 += __shfl_xor(s3, off);
        }
        if (lane == 0) {
            float4 icv = *(const float4*)(invc4 + (size_t)v * 4);
            float zsum = pz4[(size_t)v * 4 + 3];
            float val = s1 * icv.x + s2 * icv.y + s3 * icv.z + zsum;
            outp[v] = 1.f / (1.f + expf(-val));
        }
    }
}

// ---------- launch ----------
extern "C" void kernel_launch(void* const* d_in, const int* in_sizes, int n_in,
                              void* d_out, int out_size, void* d_ws, size_t ws_size,
                              hipStream_t stream)
{
    const float* x    = (const float*)d_in[0];
    const int* ei     = (const int*)d_in[1];
    const int* attr   = (const int*)d_in[2];
    const float* Wspf = (const float*)d_in[3];
    const float* bspf = (const float*)d_in[4];
    const float* W011 = (const float*)d_in[5];
    const float* b011 = (const float*)d_in[6];
    const float* W012 = (const float*)d_in[7];
    const float* b012 = (const float*)d_in[8];
    const float* bn01 = (const float*)d_in[9];
    const float* eW1[3] = { (const float*)d_in[10], (const float*)d_in[15], (const float*)d_in[20] };
    const float* eb1[3] = { (const float*)d_in[11], (const float*)d_in[16], (const float*)d_in[21] };
    const float* eW2[3] = { (const float*)d_in[12], (const float*)d_in[17], (const float*)d_in[22] };
    const float* eb2[3] = { (const float*)d_in[13], (const float*)d_in[18], (const float*)d_in[23] };
    const float* bn1[3] = { (const float*)d_in[14], (const float*)d_in[19], (const float*)d_in[24] };
    const float* s21Wl = (const float*)d_in[25];
    const float* s21bl = (const float*)d_in[26];
    const float* s21Wr = (const float*)d_in[27];
    const float* bn21  = (const float*)d_in[28];
    const float* s3Wl[3] = { (const float*)d_in[29], (const float*)d_in[32], (const float*)d_in[35] };
    const float* s3bl[3] = { (const float*)d_in[30], (const float*)d_in[33], (const float*)d_in[36] };
    const float* s3Wr[3] = { (const float*)d_in[31], (const float*)d_in[34], (const float*)d_in[37] };

    char* ws = (char*)d_ws;
    unsigned short* Whl = (unsigned short*)(ws + OFF_WHL);
    float* WspP   = (float*)(ws + OFF_WSPP);
    float* bias01 = (float*)(ws + OFF_BIAS01);
    float* W1pqT  = (float*)(ws + OFF_W1PQT);
    float* biasPQ = (float*)(ws + OFF_BIASPQ);
    float* WsageT = (float*)(ws + OFF_WSAGET);
    float* bias21 = (float*)(ws + OFF_BIAS21);
    float* bnf    = (float*)(ws + OFF_BNF);
    f16*   W2h    = (f16*)(ws + OFF_W2BF);
    float* invc4  = (float*)(ws + OFF_INVC4);
    float* pz4    = (float*)(ws + OFF_PZ4);
    int*   rp     = (int*)(ws + OFF_RP);
    int*   parts  = (int*)(ws + OFF_PARTS);
    int*   deg    = (int*)(ws + OFF_DEG);
    int*   ghead  = (int*)(ws + OFF_GHEAD);
    int*   sorted = (int*)(ws + OFF_SORT);
    unsigned int* ebuck = (unsigned int*)(ws + OFF_EBUCK);
    float* h      = (float*)(ws + OFF_H);
    f16*   Pi     = (f16*)(ws + OFF_PI);
    f16*   Qi     = (f16*)(ws + OFF_QI);
    f16*   y1i    = (f16*)(ws + OFF_Y1I);
    f16*   aggi   = (f16*)(ws + OFF_AGGI);   // overlays Pi (dead after edgeconv)

    hipMemsetAsync(ws + OFF_DEG, 0, 200064, stream);

    k_prep<<<689, 256, 0, stream>>>(
        Wspf, bspf, W011, b011, W012, b012, bn01,
        eW1[0], eb1[0], eb2[0], bn1[0],
        eW1[1], eb1[1], eb2[1], bn1[1],
        eW1[2], eb1[2], eb2[2], bn1[2],
        eW2[0], eW2[1], eW2[2],
        s21Wl, s21bl, s21Wr, bn21,
        Whl, WspP, bias01, W1pqT, biasPQ, WsageT, bias21, bnf, W2h);

    k_hist<<<3907, 256, 0, stream>>>(ei + EE, deg);
    k_psum<<<NBK, 256, 0, stream>>>(deg, parts);
    k_pscan<<<1, 256, 0, stream>>>(parts, ghead);
    k_scanfix<<<NBK, 256, 0, stream>>>(deg, parts, rp);
    k_bucketA<<<245, 256, 0, stream>>>(ei, ei + EE, attr, ghead, ebuck);
    k_bucketB<<<NBK, 256, 0, stream>>>(rp, ebuck, sorted);

    k_h<<<3125, 256, 0, stream>>>(x, Whl, WspP, bias01, h);

    k_pq<<<782, 256, 0, stream>>>(h, W1pqT, biasPQ, Pi, Qi);

    k_edgeconv_f<<<PW_EC / 4, 256, 0, stream>>>(rp, sorted, Pi, Qi, W2h, bnf, y1i, invc4);
    k_agg_f<<<PW_AG / 4, 256, 0, stream>>>(rp, sorted, y1i, invc4, aggi);

    k_sage1<<<391, 256, 0, stream>>>(aggi, y1i, WsageT, bias21,
                                     s3Wl[0], s3bl[0], s3Wr[0],
                                     s3Wl[1], s3bl[1], s3Wr[1],
                                     s3Wl[2], s3bl[2], s3Wr[2], pz4);

    k_sage2_f<<<PW_AG / 4, 256, 0, stream>>>(rp, sorted, pz4, invc4, (float*)d_out);
}